// Round 1
// baseline (334.322 us; speedup 1.0000x reference)
//
#include <hip/hip_runtime.h>

#define EPSBN 1e-3f

__device__ __forceinline__ float sigmoidf_(float z) {
  return 1.0f / (1.0f + expf(-z));
}

// ---------------- K: raw channel sums of x over H,W (atomic accum) -------------
__global__ void k_mean_x(const float* __restrict__ x, float* __restrict__ meanx_raw) {
  const int b = blockIdx.x >> 2;   // 4 blocks per batch
  const int q = blockIdx.x & 3;
  const int tid = threadIdx.x;
  float acc[6] = {0.f, 0.f, 0.f, 0.f, 0.f, 0.f};
  const float* xb = x + (size_t)b * (128 * 128 * 6);
  for (int i = 0; i < 16; ++i) {
    const int p = q * 4096 + i * 256 + tid;
    const float* px = xb + (size_t)p * 6;
#pragma unroll
    for (int c = 0; c < 6; ++c) acc[c] += px[c];
  }
#pragma unroll
  for (int c = 0; c < 6; ++c)
    for (int off = 32; off > 0; off >>= 1) acc[c] += __shfl_down(acc[c], off, 64);
  __shared__ float red[4][6];
  const int lane = tid & 63, w = tid >> 6;
  if (lane == 0) {
#pragma unroll
    for (int c = 0; c < 6; ++c) red[w][c] = acc[c];
  }
  __syncthreads();
  if (tid < 6) {
    float s = red[0][tid] + red[1][tid] + red[2][tid] + red[3][tid];
    atomicAdd(&meanx_raw[b * 6 + tid], s);
  }
}

// ------------- K: route1 + build per-example conv1 kernel (BN inv folded) ------
__global__ void k_buildk1(const float* __restrict__ meanx_raw,
                          const float* __restrict__ experts1,  // [3][3*3*6*32]
                          const float* __restrict__ rw, const float* __restrict__ rb,
                          const float* __restrict__ gamma, const float* __restrict__ var,
                          float* __restrict__ k1p) {
  const int b = blockIdx.x;
  const int tid = threadIdx.x;
  __shared__ float route[3];
  if (tid < 3) {
    float z = rb[tid];
    for (int c = 0; c < 6; ++c)
      z += (meanx_raw[b * 6 + c] * (1.0f / 16384.0f)) * rw[c * 3 + tid];
    route[tid] = sigmoidf_(z);
  }
  __syncthreads();
  const float r0 = route[0], r1 = route[1], r2 = route[2];
  for (int t = tid; t < 1728; t += 256) {
    const int co = t & 31;
    const float inv = gamma[co] * rsqrtf(var[co] + EPSBN);
    const float v = r0 * experts1[t] + r1 * experts1[1728 + t] + r2 * experts1[2 * 1728 + t];
    k1p[(size_t)b * 1728 + t] = v * inv;
  }
}

// ------------- K: conv1 (3x3, Cin=6, Cout=32) + bias + relu + maxpool2 ---------
// grid: 64 batches x 16 tiles; tile = 32x32 conv region -> 16x16 pooled.
// output p1 planar [b][co][64][64]
__global__ __launch_bounds__(256, 3)
void k_conv1(const float* __restrict__ x, const float* __restrict__ k1p,
             const float* __restrict__ gamma, const float* __restrict__ beta,
             const float* __restrict__ bnmean, const float* __restrict__ bnvar,
             float* __restrict__ p1) {
  const int b = blockIdx.x >> 4;
  const int tile = blockIdx.x & 15;
  const int ty = tile >> 2, tx = tile & 3;
  __shared__ float in_s[6 * 34 * 35];  // planar [ci][34][35-pad]
  const int tid = threadIdx.x;
  const float* xb = x + (size_t)b * (128 * 128 * 6);
  for (int p = tid; p < 34 * 34; p += 256) {
    const int ly = p / 34, lx = p - ly * 34;
    const int gy = ty * 32 - 1 + ly, gx = tx * 32 - 1 + lx;
    const bool ok = ((unsigned)gy < 128u) && ((unsigned)gx < 128u);
    const float* src = xb + ((size_t)(gy * 128 + gx)) * 6;
#pragma unroll
    for (int c = 0; c < 6; ++c)
      in_s[(c * 34 + ly) * 35 + lx] = ok ? src[c] : 0.0f;
  }
  __syncthreads();
  const int py = tid >> 4, px = tid & 15;
  const float* kb = k1p + (size_t)b * 1728;
  for (int cog = 0; cog < 2; ++cog) {
    float acc[2][2][16];
#pragma unroll
    for (int a = 0; a < 2; ++a)
#pragma unroll
      for (int bb = 0; bb < 2; ++bb)
#pragma unroll
        for (int k = 0; k < 16; ++k) acc[a][bb][k] = 0.f;
    for (int ky = 0; ky < 3; ++ky)
      for (int kx = 0; kx < 3; ++kx) {
#pragma unroll
        for (int ci = 0; ci < 6; ++ci) {
          const int woff = ((ky * 3 + kx) * 6 + ci) * 32 + cog * 16;
          float w[16];
#pragma unroll
          for (int k = 0; k < 16; ++k) w[k] = kb[woff + k];  // uniform -> s_load
          const float* ra = &in_s[(ci * 34 + 2 * py + ky) * 35 + 2 * px + kx];
          const float* rb2 = ra + 35;
          const float v00 = ra[0], v01 = ra[1], v10 = rb2[0], v11 = rb2[1];
#pragma unroll
          for (int k = 0; k < 16; ++k) {
            acc[0][0][k] = fmaf(v00, w[k], acc[0][0][k]);
            acc[0][1][k] = fmaf(v01, w[k], acc[0][1][k]);
            acc[1][0][k] = fmaf(v10, w[k], acc[1][0][k]);
            acc[1][1][k] = fmaf(v11, w[k], acc[1][1][k]);
          }
        }
      }
#pragma unroll
    for (int k = 0; k < 16; ++k) {
      const int co = cog * 16 + k;
      const float inv = gamma[co] * rsqrtf(bnvar[co] + EPSBN);
      const float bias = beta[co] - bnmean[co] * inv;
      const float m0 = fmaxf(acc[0][0][k] + bias, 0.f);
      const float m1 = fmaxf(acc[0][1][k] + bias, 0.f);
      const float m2 = fmaxf(acc[1][0][k] + bias, 0.f);
      const float m3 = fmaxf(acc[1][1][k] + bias, 0.f);
      const float mx = fmaxf(fmaxf(m0, m1), fmaxf(m2, m3));
      p1[(((size_t)b * 32 + co) * 64 + (ty * 16 + py)) * 64 + (tx * 16 + px)] = mx;
    }
  }
}

// ------------- K: per-(b,c) mean of p1 (one wave per 64x64 plane) --------------
__global__ void k_mean1(const float* __restrict__ p1, float* __restrict__ mean1_raw) {
  const int b = blockIdx.x >> 3, cb = blockIdx.x & 7;
  const int w = threadIdx.x >> 6, lane = threadIdx.x & 63;
  const int c = cb * 4 + w;
  const float* plane = p1 + ((size_t)b * 32 + c) * 4096;
  float s = 0.f;
  for (int i = 0; i < 64; ++i) s += plane[i * 64 + lane];
  for (int off = 32; off > 0; off >>= 1) s += __shfl_down(s, off, 64);
  if (lane == 0) mean1_raw[b * 32 + c] = s;
}

// ------------- K: SE1 + route2 + build k2' (SE s1[ci] and BN inv2[co] folded) --
__global__ void k_buildk2(const float* __restrict__ mean1_raw,
                          const float* __restrict__ experts2,  // [3][3*3*32*64]
                          const float* __restrict__ rw, const float* __restrict__ rb,
                          const float* __restrict__ w1, const float* __restrict__ w2,
                          const float* __restrict__ gamma, const float* __restrict__ var,
                          float* __restrict__ k2p) {
  const int b = blockIdx.x, tid = threadIdx.x;
  __shared__ float m1[32], h[2], s1[32], route[3];
  if (tid < 32) m1[tid] = mean1_raw[b * 32 + tid] * (1.0f / 4096.0f);
  __syncthreads();
  if (tid < 2) {
    float z = 0.f;
    for (int c = 0; c < 32; ++c) z += m1[c] * w1[c * 2 + tid];
    h[tid] = fmaxf(z, 0.f);
  }
  __syncthreads();
  if (tid < 32) s1[tid] = sigmoidf_(h[0] * w2[tid] + h[1] * w2[32 + tid]);
  __syncthreads();
  if (tid < 3) {
    float z = rb[tid];
    for (int c = 0; c < 32; ++c) z += m1[c] * s1[c] * rw[c * 3 + tid];
    route[tid] = sigmoidf_(z);
  }
  __syncthreads();
  const float r0 = route[0], r1 = route[1], r2 = route[2];
  for (int t = tid; t < 18432; t += 256) {
    const int co = t & 63;
    const int ci = (t >> 6) & 31;
    const float inv = gamma[co] * rsqrtf(var[co] + EPSBN);
    const float v = r0 * experts2[t] + r1 * experts2[18432 + t] + r2 * experts2[2 * 18432 + t];
    k2p[(size_t)b * 18432 + t] = v * s1[ci] * inv;
  }
}

// ------------- K: conv2 (3x3, Cin=32, Cout=64) + bias + relu + maxpool2 --------
// grid: 64 batches x 16 tiles; tile = 16x16 conv region -> 8x8 pooled.
// p1 planar in, p2 planar [b][co][32][32] out. ci chunked by 8 through LDS.
__global__ __launch_bounds__(256, 3)
void k_conv2(const float* __restrict__ p1, const float* __restrict__ k2p,
             const float* __restrict__ gamma, const float* __restrict__ beta,
             const float* __restrict__ bnmean, const float* __restrict__ bnvar,
             float* __restrict__ p2) {
  const int b = blockIdx.x >> 4;
  const int tile = blockIdx.x & 15;
  const int ty = tile >> 2, tx = tile & 3;
  __shared__ float in_s[8 * 18 * 19];  // planar [ci_local][18][19-pad]
  const int tid = threadIdx.x;
  const int g = __builtin_amdgcn_readfirstlane(tid >> 6);  // co group (16 co per wave)
  const int lane = tid & 63;
  const int py = lane >> 3, px = lane & 7;
  float acc[2][2][16];
#pragma unroll
  for (int a = 0; a < 2; ++a)
#pragma unroll
    for (int bb = 0; bb < 2; ++bb)
#pragma unroll
      for (int k = 0; k < 16; ++k) acc[a][bb][k] = 0.f;
  const float* kb = k2p + (size_t)b * 18432 + g * 16;
  for (int cc = 0; cc < 4; ++cc) {
    if (cc) __syncthreads();
    for (int idx = tid; idx < 8 * 18 * 18; idx += 256) {
      const int ci = idx / 324;
      const int rem = idx - ci * 324;
      const int r = rem / 18, c = rem - r * 18;
      const int gy = ty * 16 - 1 + r, gx = tx * 16 - 1 + c;
      const bool ok = ((unsigned)gy < 64u) && ((unsigned)gx < 64u);
      in_s[(ci * 18 + r) * 19 + c] =
          ok ? p1[(((size_t)b * 32 + cc * 8 + ci) * 64 + gy) * 64 + gx] : 0.f;
    }
    __syncthreads();
    for (int ky = 0; ky < 3; ++ky)
      for (int kx = 0; kx < 3; ++kx) {
#pragma unroll
        for (int ci = 0; ci < 8; ++ci) {
          const int woff = ((ky * 3 + kx) * 32 + cc * 8 + ci) * 64;
          float w[16];
#pragma unroll
          for (int k = 0; k < 16; ++k) w[k] = kb[woff + k];  // uniform -> s_load
          const float* ra = &in_s[(ci * 18 + 2 * py + ky) * 19 + 2 * px + kx];
          const float* rb2 = ra + 19;
          const float v00 = ra[0], v01 = ra[1], v10 = rb2[0], v11 = rb2[1];
#pragma unroll
          for (int k = 0; k < 16; ++k) {
            acc[0][0][k] = fmaf(v00, w[k], acc[0][0][k]);
            acc[0][1][k] = fmaf(v01, w[k], acc[0][1][k]);
            acc[1][0][k] = fmaf(v10, w[k], acc[1][0][k]);
            acc[1][1][k] = fmaf(v11, w[k], acc[1][1][k]);
          }
        }
      }
  }
#pragma unroll
  for (int k = 0; k < 16; ++k) {
    const int co = g * 16 + k;
    const float inv = gamma[co] * rsqrtf(bnvar[co] + EPSBN);
    const float bias = beta[co] - bnmean[co] * inv;
    const float m0 = fmaxf(acc[0][0][k] + bias, 0.f);
    const float m1 = fmaxf(acc[0][1][k] + bias, 0.f);
    const float m2 = fmaxf(acc[1][0][k] + bias, 0.f);
    const float m3 = fmaxf(acc[1][1][k] + bias, 0.f);
    const float mx = fmaxf(fmaxf(m0, m1), fmaxf(m2, m3));
    p2[(((size_t)b * 64 + co) * 32 + (ty * 8 + py)) * 32 + (tx * 8 + px)] = mx;
  }
}

// ------------- K: stage-3 shifted plane sums S[b][9][ci] from p2 ---------------
// mean over spatial of SAME 3x3 conv == linear combo of 9 shifted sums.
// One wave per (b,ci) 32x32 plane.
__global__ void k_s3(const float* __restrict__ p2, float* __restrict__ S_raw) {
  const int b = blockIdx.x >> 4, cb = blockIdx.x & 15;
  const int w = threadIdx.x >> 6, lane = threadIdx.x & 63;
  const int ci = cb * 4 + w;
  const float* plane = p2 + ((size_t)b * 64 + ci) * 1024;
  float t = 0.f, r0 = 0.f, rl = 0.f, c0 = 0.f, cl = 0.f;
  float k00 = 0.f, k01 = 0.f, k10 = 0.f, k11 = 0.f;  // corners in[0][0],[0][31],[31][0],[31][31]
  const int c = lane & 31;
#pragma unroll
  for (int i = 0; i < 16; ++i) {
    const int idx = i * 64 + lane;
    const float v = plane[idx];
    const int r = idx >> 5;
    t += v;
    if (r == 0) r0 += v;
    if (r == 31) rl += v;
    if (c == 0) c0 += v;
    if (c == 31) cl += v;
    if (r == 0 && c == 0) k00 = v;
    if (r == 0 && c == 31) k01 = v;
    if (r == 31 && c == 0) k10 = v;
    if (r == 31 && c == 31) k11 = v;
  }
  for (int off = 32; off > 0; off >>= 1) {
    t += __shfl_down(t, off, 64);
    r0 += __shfl_down(r0, off, 64);
    rl += __shfl_down(rl, off, 64);
    c0 += __shfl_down(c0, off, 64);
    cl += __shfl_down(cl, off, 64);
    k00 += __shfl_down(k00, off, 64);
    k01 += __shfl_down(k01, off, 64);
    k10 += __shfl_down(k10, off, 64);
    k11 += __shfl_down(k11, off, 64);
  }
  if (lane == 0) {
    // ky=0 excludes last row, ky=2 excludes row 0; kx likewise for cols.
    const float A[3] = {rl, 0.f, r0};
    const float B[3] = {cl, 0.f, c0};
    const float AB[3][3] = {{k11, 0.f, k10}, {0.f, 0.f, 0.f}, {k01, 0.f, k00}};
#pragma unroll
    for (int ky = 0; ky < 3; ++ky)
#pragma unroll
      for (int kx = 0; kx < 3; ++kx)
        S_raw[((size_t)b * 9 + ky * 3 + kx) * 64 + ci] = t - A[ky] - B[kx] + AB[ky][kx];
  }
}

// ------------- K: SE2 + route3 + stage-3 contraction + BN3 + final mean --------
// grid: 64 batches x 9 taps; block 128 threads (one per output channel).
// atomicAdd partial tap contributions into out (out pre-zeroed).
__global__ void k_final(const float* __restrict__ S_raw, const float* __restrict__ experts3,
                        const float* __restrict__ rw, const float* __restrict__ rb,
                        const float* __restrict__ w1, const float* __restrict__ w2,
                        const float* __restrict__ gamma, const float* __restrict__ beta,
                        const float* __restrict__ bnmean, const float* __restrict__ bnvar,
                        float* __restrict__ out) {
  const int b = blockIdx.x / 9;
  const int tap = blockIdx.x - b * 9;
  const int tid = threadIdx.x;
  __shared__ float m2[64], h[4], s2[64], route[3], Sp[64];
  if (tid < 64) m2[tid] = S_raw[((size_t)b * 9 + 4) * 64 + tid] * (1.0f / 1024.0f);
  __syncthreads();
  if (tid < 4) {
    float z = 0.f;
    for (int ccc = 0; ccc < 64; ++ccc) z += m2[ccc] * w1[ccc * 4 + tid];
    h[tid] = fmaxf(z, 0.f);
  }
  __syncthreads();
  if (tid < 64) {
    float z = 0.f;
#pragma unroll
    for (int j = 0; j < 4; ++j) z += h[j] * w2[j * 64 + tid];
    s2[tid] = sigmoidf_(z);
  }
  __syncthreads();
  if (tid < 3) {
    float z = rb[tid];
    for (int ccc = 0; ccc < 64; ++ccc) z += m2[ccc] * s2[ccc] * rw[ccc * 3 + tid];
    route[tid] = sigmoidf_(z);
  }
  __syncthreads();
  if (tid < 64) Sp[tid] = S_raw[((size_t)b * 9 + tap) * 64 + tid] * s2[tid];
  __syncthreads();

  float acc = 0.f;
#pragma unroll
  for (int e = 0; e < 3; ++e) {
    float m = 0.f;
    const float* E = experts3 + ((size_t)(e * 9 + tap) * 64) * 128 + tid;
#pragma unroll 16
    for (int ccc = 0; ccc < 64; ++ccc) m = fmaf(E[(size_t)ccc * 128], Sp[ccc], m);
    acc += route[e] * m;
  }
  const float inv = gamma[tid] * rsqrtf(bnvar[tid] + EPSBN);
  float contrib = (acc * (1.0f / 1024.0f)) * inv;
  if (tap == 4) contrib += beta[tid] - bnmean[tid] * inv;
  atomicAdd(&out[b * 128 + tid], contrib);
}

extern "C" void kernel_launch(void* const* d_in, const int* in_sizes, int n_in,
                              void* d_out, int out_size, void* d_ws, size_t ws_size,
                              hipStream_t stream) {
  const float* x        = (const float*)d_in[0];
  const float* experts1 = (const float*)d_in[1];
  const float* rw1      = (const float*)d_in[2];
  const float* rb1      = (const float*)d_in[3];
  const float* g1  = (const float*)d_in[4];
  const float* be1 = (const float*)d_in[5];
  const float* mu1 = (const float*)d_in[6];
  const float* va1 = (const float*)d_in[7];
  const float* sw1a = (const float*)d_in[8];
  const float* sw1b = (const float*)d_in[9];
  const float* experts2 = (const float*)d_in[10];
  const float* rw2 = (const float*)d_in[11];
  const float* rb2 = (const float*)d_in[12];
  const float* g2  = (const float*)d_in[13];
  const float* be2 = (const float*)d_in[14];
  const float* mu2 = (const float*)d_in[15];
  const float* va2 = (const float*)d_in[16];
  const float* sw2a = (const float*)d_in[17];
  const float* sw2b = (const float*)d_in[18];
  const float* experts3 = (const float*)d_in[19];
  const float* rw3 = (const float*)d_in[20];
  const float* rb3 = (const float*)d_in[21];
  const float* g3  = (const float*)d_in[22];
  const float* be3 = (const float*)d_in[23];
  const float* mu3 = (const float*)d_in[24];
  const float* va3 = (const float*)d_in[25];
  float* out = (float*)d_out;
  float* ws = (float*)d_ws;

  // workspace layout (floats); total ~13.92M floats = 55.7 MB
  float* meanx_raw = ws;              // 384
  float* k1p       = ws + 384;        // 110592
  float* mean1_raw = ws + 110976;     // 2048
  float* k2p       = ws + 113024;     // 1179648
  float* S_raw     = ws + 1292672;    // 36864
  float* p1        = ws + 1329536;    // 8388608  [64][32][64][64]
  float* p2        = ws + 9718144;    // 4194304  [64][64][32][32]

  hipMemsetAsync(meanx_raw, 0, 384 * sizeof(float), stream);
  hipMemsetAsync(d_out, 0, (size_t)out_size * sizeof(float), stream);

  hipLaunchKernelGGL(k_mean_x, dim3(256), dim3(256), 0, stream, x, meanx_raw);
  hipLaunchKernelGGL(k_buildk1, dim3(64), dim3(256), 0, stream,
                     meanx_raw, experts1, rw1, rb1, g1, va1, k1p);
  hipLaunchKernelGGL(k_conv1, dim3(1024), dim3(256), 0, stream,
                     x, k1p, g1, be1, mu1, va1, p1);
  hipLaunchKernelGGL(k_mean1, dim3(512), dim3(256), 0, stream, p1, mean1_raw);
  hipLaunchKernelGGL(k_buildk2, dim3(64), dim3(256), 0, stream,
                     mean1_raw, experts2, rw2, rb2, sw1a, sw1b, g2, va2, k2p);
  hipLaunchKernelGGL(k_conv2, dim3(1024), dim3(256), 0, stream,
                     p1, k2p, g2, be2, mu2, va2, p2);
  hipLaunchKernelGGL(k_s3, dim3(1024), dim3(256), 0, stream, p2, S_raw);
  hipLaunchKernelGGL(k_final, dim3(576), dim3(128), 0, stream,
                     S_raw, experts3, rw3, rb3, sw2a, sw2b, g3, be3, mu3, va3, out);
}

// Round 2
// 245.459 us; speedup vs baseline: 1.3620x; 1.3620x over previous
//
#include <hip/hip_runtime.h>

#define EPSBN 1e-3f

typedef unsigned short ushort_t;
typedef __attribute__((ext_vector_type(8))) short bf8;   // 8 bf16 = 4 VGPRs
typedef __attribute__((ext_vector_type(4))) float f4;

__device__ __forceinline__ float sigmoidf_(float z) {
  return 1.0f / (1.0f + expf(-z));
}

__device__ __forceinline__ ushort_t f2bf(float x) {  // RTNE
  union { float f; unsigned u; } v; v.f = x;
  unsigned r = (v.u + 0x7fffu + ((v.u >> 16) & 1u)) >> 16;
  return (ushort_t)r;
}

__device__ __forceinline__ float bfbits2f(unsigned hi_bits) {  // already shifted <<16 or masked
  union { unsigned u; float f; } v; v.u = hi_bits;
  return v.f;
}

// ---------------- K: raw channel sums of x over H,W (atomic accum) -------------
__global__ void k_mean_x(const float* __restrict__ x, float* __restrict__ meanx_raw) {
  const int b = blockIdx.x >> 2;
  const int q = blockIdx.x & 3;
  const int tid = threadIdx.x;
  float acc[6] = {0.f, 0.f, 0.f, 0.f, 0.f, 0.f};
  const float* xb = x + (size_t)b * (128 * 128 * 6);
  for (int i = 0; i < 16; ++i) {
    const int p = q * 4096 + i * 256 + tid;
    const float* px = xb + (size_t)p * 6;
#pragma unroll
    for (int c = 0; c < 6; ++c) acc[c] += px[c];
  }
#pragma unroll
  for (int c = 0; c < 6; ++c)
    for (int off = 32; off > 0; off >>= 1) acc[c] += __shfl_down(acc[c], off, 64);
  __shared__ float red[4][6];
  const int lane = tid & 63, w = tid >> 6;
  if (lane == 0) {
#pragma unroll
    for (int c = 0; c < 6; ++c) red[w][c] = acc[c];
  }
  __syncthreads();
  if (tid < 6) {
    float s = red[0][tid] + red[1][tid] + red[2][tid] + red[3][tid];
    atomicAdd(&meanx_raw[b * 6 + tid], s);
  }
}

// ------------- K: route1 + build per-example conv1 kernel (BN inv folded) ------
__global__ void k_buildk1(const float* __restrict__ meanx_raw,
                          const float* __restrict__ experts1,
                          const float* __restrict__ rw, const float* __restrict__ rb,
                          const float* __restrict__ gamma, const float* __restrict__ var,
                          float* __restrict__ k1p) {
  const int b = blockIdx.x;
  const int tid = threadIdx.x;
  __shared__ float route[3];
  if (tid < 3) {
    float z = rb[tid];
    for (int c = 0; c < 6; ++c)
      z += (meanx_raw[b * 6 + c] * (1.0f / 16384.0f)) * rw[c * 3 + tid];
    route[tid] = sigmoidf_(z);
  }
  __syncthreads();
  const float r0 = route[0], r1 = route[1], r2 = route[2];
  for (int t = tid; t < 1728; t += 256) {
    const int co = t & 31;
    const float inv = gamma[co] * rsqrtf(var[co] + EPSBN);
    const float v = r0 * experts1[t] + r1 * experts1[1728 + t] + r2 * experts1[2 * 1728 + t];
    k1p[(size_t)b * 1728 + t] = v * inv;
  }
}

// ------------- K: conv1 (3x3, Cin=6, Cout=32) + bias + relu + maxpool2 ---------
// output p1b interleaved bf16 [b][64][64][32]
__global__ __launch_bounds__(256, 3)
void k_conv1(const float* __restrict__ x, const float* __restrict__ k1p,
             const float* __restrict__ gamma, const float* __restrict__ beta,
             const float* __restrict__ bnmean, const float* __restrict__ bnvar,
             ushort_t* __restrict__ p1b) {
  const int b = blockIdx.x >> 4;
  const int tile = blockIdx.x & 15;
  const int ty = tile >> 2, tx = tile & 3;
  __shared__ float in_s[6 * 34 * 35];
  const int tid = threadIdx.x;
  const float* xb = x + (size_t)b * (128 * 128 * 6);
  for (int p = tid; p < 34 * 34; p += 256) {
    const int ly = p / 34, lx = p - ly * 34;
    const int gy = ty * 32 - 1 + ly, gx = tx * 32 - 1 + lx;
    const bool ok = ((unsigned)gy < 128u) && ((unsigned)gx < 128u);
    const float* src = xb + ((size_t)(gy * 128 + gx)) * 6;
#pragma unroll
    for (int c = 0; c < 6; ++c)
      in_s[(c * 34 + ly) * 35 + lx] = ok ? src[c] : 0.0f;
  }
  __syncthreads();
  const int py = tid >> 4, px = tid & 15;
  const float* kb = k1p + (size_t)b * 1728;
  for (int cog = 0; cog < 2; ++cog) {
    float acc[2][2][16];
#pragma unroll
    for (int a = 0; a < 2; ++a)
#pragma unroll
      for (int bb = 0; bb < 2; ++bb)
#pragma unroll
        for (int k = 0; k < 16; ++k) acc[a][bb][k] = 0.f;
    for (int ky = 0; ky < 3; ++ky)
      for (int kx = 0; kx < 3; ++kx) {
#pragma unroll
        for (int ci = 0; ci < 6; ++ci) {
          const int woff = ((ky * 3 + kx) * 6 + ci) * 32 + cog * 16;
          float w[16];
#pragma unroll
          for (int k = 0; k < 16; ++k) w[k] = kb[woff + k];
          const float* ra = &in_s[(ci * 34 + 2 * py + ky) * 35 + 2 * px + kx];
          const float* rb2 = ra + 35;
          const float v00 = ra[0], v01 = ra[1], v10 = rb2[0], v11 = rb2[1];
#pragma unroll
          for (int k = 0; k < 16; ++k) {
            acc[0][0][k] = fmaf(v00, w[k], acc[0][0][k]);
            acc[0][1][k] = fmaf(v01, w[k], acc[0][1][k]);
            acc[1][0][k] = fmaf(v10, w[k], acc[1][0][k]);
            acc[1][1][k] = fmaf(v11, w[k], acc[1][1][k]);
          }
        }
      }
    __align__(16) ushort_t vals[16];
#pragma unroll
    for (int k = 0; k < 16; ++k) {
      const int co = cog * 16 + k;
      const float inv = gamma[co] * rsqrtf(bnvar[co] + EPSBN);
      const float bias = beta[co] - bnmean[co] * inv;
      const float m0 = fmaxf(acc[0][0][k] + bias, 0.f);
      const float m1 = fmaxf(acc[0][1][k] + bias, 0.f);
      const float m2 = fmaxf(acc[1][0][k] + bias, 0.f);
      const float m3 = fmaxf(acc[1][1][k] + bias, 0.f);
      vals[k] = f2bf(fmaxf(fmaxf(m0, m1), fmaxf(m2, m3)));
    }
    uint4* dst = (uint4*)(p1b + (((size_t)b * 64 + (ty * 16 + py)) * 64 + (tx * 16 + px)) * 32 + cog * 16);
    dst[0] = ((uint4*)vals)[0];
    dst[1] = ((uint4*)vals)[1];
  }
}

// ------------- K: per-(b,c) channel sums of p1b (one block per batch) ----------
__global__ void k_mean1(const ushort_t* __restrict__ p1b, float* __restrict__ mean1_raw) {
  const int b = blockIdx.x, tid = threadIdx.x;
  const int oct = tid & 3, row0 = tid >> 2;
  const ushort_t* base = p1b + (size_t)b * 131072;
  float s[8] = {0.f, 0.f, 0.f, 0.f, 0.f, 0.f, 0.f, 0.f};
  for (int k = 0; k < 64; ++k) {
    const int pos = (k << 6) + row0;
    const uint4 u = *(const uint4*)(base + (size_t)pos * 32 + oct * 8);
    const unsigned uu[4] = {u.x, u.y, u.z, u.w};
#pragma unroll
    for (int j = 0; j < 4; ++j) {
      s[2 * j]     += bfbits2f(uu[j] << 16);
      s[2 * j + 1] += bfbits2f(uu[j] & 0xffff0000u);
    }
  }
  __shared__ float red[256][8];
#pragma unroll
  for (int j = 0; j < 8; ++j) red[tid][j] = s[j];
  __syncthreads();
  if (tid < 32) {
    float t = 0.f;
    const int o = tid >> 3, j = tid & 7;
    for (int r = 0; r < 64; ++r) t += red[r * 4 + o][j];
    mean1_raw[b * 32 + tid] = t;
  }
}

// ------------- K: SE1 + route2 + build k2' bf16 [b][tap][co][ci] ---------------
__global__ void k_buildk2(const float* __restrict__ mean1_raw,
                          const float* __restrict__ experts2,
                          const float* __restrict__ rw, const float* __restrict__ rb,
                          const float* __restrict__ w1, const float* __restrict__ w2,
                          const float* __restrict__ gamma, const float* __restrict__ var,
                          ushort_t* __restrict__ k2pb) {
  const int b = blockIdx.x, tid = threadIdx.x;
  __shared__ float m1[32], h[2], s1[32], route[3];
  if (tid < 32) m1[tid] = mean1_raw[b * 32 + tid] * (1.0f / 4096.0f);
  __syncthreads();
  if (tid < 2) {
    float z = 0.f;
    for (int c = 0; c < 32; ++c) z += m1[c] * w1[c * 2 + tid];
    h[tid] = fmaxf(z, 0.f);
  }
  __syncthreads();
  if (tid < 32) s1[tid] = sigmoidf_(h[0] * w2[tid] + h[1] * w2[32 + tid]);
  __syncthreads();
  if (tid < 3) {
    float z = rb[tid];
    for (int c = 0; c < 32; ++c) z += m1[c] * s1[c] * rw[c * 3 + tid];
    route[tid] = sigmoidf_(z);
  }
  __syncthreads();
  const float r0 = route[0], r1 = route[1], r2 = route[2];
  for (int t = tid; t < 18432; t += 256) {
    const int co = t & 63;
    const int ci = (t >> 6) & 31;
    const int tap = t >> 11;
    const float inv = gamma[co] * rsqrtf(var[co] + EPSBN);
    const float v = r0 * experts2[t] + r1 * experts2[18432 + t] + r2 * experts2[2 * 18432 + t];
    k2pb[(size_t)b * 18432 + ((size_t)tap * 64 + co) * 32 + ci] = f2bf(v * s1[ci] * inv);
  }
}

// ------------- K: conv2 via MFMA implicit GEMM + bias + relu + maxpool2 --------
// grid: 64 b x 16 tiles x 2 co-groups. Block: 256 thr (4 waves).
// A LDS [18][18][40-pitch] bf16; B LDS [9*32 rows][40-pitch] bf16.
// MFMA 16x16x32 bf16: one MFMA covers one tap's full 32-ci dot.
__global__ __launch_bounds__(256)
void k_conv2(const ushort_t* __restrict__ p1b, const ushort_t* __restrict__ k2pb,
             const float* __restrict__ gamma, const float* __restrict__ beta,
             const float* __restrict__ bnmean, const float* __restrict__ bnvar,
             float* __restrict__ p2) {
  const int bi = blockIdx.x;
  const int b = bi >> 5;
  const int tile = (bi >> 1) & 15;
  const int cog = bi & 1;
  const int ty = tile >> 2, tx = tile & 3;
  __shared__ __align__(16) short smem[24480];  // A: 12960 shorts, B: 11520 shorts
  short* As = smem;
  short* Bs = smem + 12960;
  const int tid = threadIdx.x;

  // stage A: [18][18][32ci] -> pitch 40
  const ushort_t* pb = p1b + (size_t)b * 131072;
  for (int v = tid; v < 1296; v += 256) {
    const int cell = v >> 2, part = v & 3;
    const int ly = cell / 18, lx2 = cell - ly * 18;
    const int gy = ty * 16 - 1 + ly, gx = tx * 16 - 1 + lx2;
    uint4 d = make_uint4(0u, 0u, 0u, 0u);
    if (((unsigned)gy < 64u) && ((unsigned)gx < 64u))
      d = *(const uint4*)(pb + (((size_t)gy << 6) + gx) * 32 + part * 8);
    *(uint4*)(As + (ly * 18 + lx2) * 40 + part * 8) = d;
  }
  // stage B: rows r = tap*32 + n (n = local co), 32 ci -> pitch 40
  for (int v = tid; v < 1152; v += 256) {
    const int r = v >> 2, part = v & 3;
    const int t = r >> 5, n = r & 31;
    const uint4 d = *(const uint4*)(k2pb + (size_t)b * 18432 +
                                    ((size_t)(t * 64 + cog * 32 + n)) * 32 + part * 8);
    *(uint4*)(Bs + r * 40 + part * 8) = d;
  }
  __syncthreads();

  const int w = tid >> 6;
  const int lane = tid & 63;
  const int lx = lane & 15, lg = lane >> 4;

  f4 acc[4][2];
#pragma unroll
  for (int mt = 0; mt < 4; ++mt)
#pragma unroll
    for (int nt = 0; nt < 2; ++nt)
      acc[mt][nt] = (f4){0.f, 0.f, 0.f, 0.f};

#pragma unroll
  for (int t = 0; t < 9; ++t) {
    const int ky = t / 3, kx = t - 3 * (t / 3);
    bf8 Bf0 = *(const bf8*)(Bs + ((t << 5) + lx) * 40 + (lg << 3));
    bf8 Bf1 = *(const bf8*)(Bs + ((t << 5) + 16 + lx) * 40 + (lg << 3));
#pragma unroll
    for (int mt = 0; mt < 4; ++mt) {
      const int y = 4 * w + mt + ky;
      const bf8 Af = *(const bf8*)(As + (y * 18 + lx + kx) * 40 + (lg << 3));
      acc[mt][0] = __builtin_amdgcn_mfma_f32_16x16x32_bf16(Af, Bf0, acc[mt][0], 0, 0, 0);
      acc[mt][1] = __builtin_amdgcn_mfma_f32_16x16x32_bf16(Af, Bf1, acc[mt][1], 0, 0, 0);
    }
  }

  // epilogue: C row = x = 4*lg + reg, col = co_local = nt*16 + lx. Maxpool 2x2.
#pragma unroll
  for (int nt = 0; nt < 2; ++nt) {
    const int co = cog * 32 + nt * 16 + lx;
    const float inv = gamma[co] * rsqrtf(bnvar[co] + EPSBN);
    const float bias = beta[co] - bnmean[co] * inv;
#pragma unroll
    for (int half = 0; half < 2; ++half) {  // rows (4w+2*half, 4w+2*half+1)
      const int prow = ty * 8 + 2 * w + half;
#pragma unroll
      for (int q = 0; q < 2; ++q) {  // regs (2q, 2q+1) -> pooled x = 2*lg + q
        const float m0 = fmaxf(acc[2 * half][nt][2 * q] + bias, 0.f);
        const float m1 = fmaxf(acc[2 * half][nt][2 * q + 1] + bias, 0.f);
        const float m2 = fmaxf(acc[2 * half + 1][nt][2 * q] + bias, 0.f);
        const float m3 = fmaxf(acc[2 * half + 1][nt][2 * q + 1] + bias, 0.f);
        const float mx = fmaxf(fmaxf(m0, m1), fmaxf(m2, m3));
        p2[(((size_t)b * 64 + co) * 32 + prow) * 32 + tx * 8 + 2 * lg + q] = mx;
      }
    }
  }
}

// ------------- K: stage-3 shifted plane sums S[b][9][ci] from p2 ---------------
__global__ void k_s3(const float* __restrict__ p2, float* __restrict__ S_raw) {
  const int b = blockIdx.x >> 4, cb = blockIdx.x & 15;
  const int w = threadIdx.x >> 6, lane = threadIdx.x & 63;
  const int ci = cb * 4 + w;
  const float* plane = p2 + ((size_t)b * 64 + ci) * 1024;
  float t = 0.f, r0 = 0.f, rl = 0.f, c0 = 0.f, cl = 0.f;
  float k00 = 0.f, k01 = 0.f, k10 = 0.f, k11 = 0.f;
  const int c = lane & 31;
#pragma unroll
  for (int i = 0; i < 16; ++i) {
    const int idx = i * 64 + lane;
    const float v = plane[idx];
    const int r = idx >> 5;
    t += v;
    if (r == 0) r0 += v;
    if (r == 31) rl += v;
    if (c == 0) c0 += v;
    if (c == 31) cl += v;
    if (r == 0 && c == 0) k00 = v;
    if (r == 0 && c == 31) k01 = v;
    if (r == 31 && c == 0) k10 = v;
    if (r == 31 && c == 31) k11 = v;
  }
  for (int off = 32; off > 0; off >>= 1) {
    t += __shfl_down(t, off, 64);
    r0 += __shfl_down(r0, off, 64);
    rl += __shfl_down(rl, off, 64);
    c0 += __shfl_down(c0, off, 64);
    cl += __shfl_down(cl, off, 64);
    k00 += __shfl_down(k00, off, 64);
    k01 += __shfl_down(k01, off, 64);
    k10 += __shfl_down(k10, off, 64);
    k11 += __shfl_down(k11, off, 64);
  }
  if (lane == 0) {
    const float A[3] = {rl, 0.f, r0};
    const float B[3] = {cl, 0.f, c0};
    const float AB[3][3] = {{k11, 0.f, k10}, {0.f, 0.f, 0.f}, {k01, 0.f, k00}};
#pragma unroll
    for (int ky = 0; ky < 3; ++ky)
#pragma unroll
      for (int kx = 0; kx < 3; ++kx)
        S_raw[((size_t)b * 9 + ky * 3 + kx) * 64 + ci] = t - A[ky] - B[kx] + AB[ky][kx];
  }
}

// ------------- K: SE2 + route3 + stage-3 contraction + BN3 + final mean --------
__global__ void k_final(const float* __restrict__ S_raw, const float* __restrict__ experts3,
                        const float* __restrict__ rw, const float* __restrict__ rb,
                        const float* __restrict__ w1, const float* __restrict__ w2,
                        const float* __restrict__ gamma, const float* __restrict__ beta,
                        const float* __restrict__ bnmean, const float* __restrict__ bnvar,
                        float* __restrict__ out) {
  const int b = blockIdx.x / 9;
  const int tap = blockIdx.x - b * 9;
  const int tid = threadIdx.x;
  __shared__ float m2[64], h[4], s2[64], route[3], Sp[64];
  if (tid < 64) m2[tid] = S_raw[((size_t)b * 9 + 4) * 64 + tid] * (1.0f / 1024.0f);
  __syncthreads();
  if (tid < 4) {
    float z = 0.f;
    for (int ccc = 0; ccc < 64; ++ccc) z += m2[ccc] * w1[ccc * 4 + tid];
    h[tid] = fmaxf(z, 0.f);
  }
  __syncthreads();
  if (tid < 64) {
    float z = 0.f;
#pragma unroll
    for (int j = 0; j < 4; ++j) z += h[j] * w2[j * 64 + tid];
    s2[tid] = sigmoidf_(z);
  }
  __syncthreads();
  if (tid < 3) {
    float z = rb[tid];
    for (int ccc = 0; ccc < 64; ++ccc) z += m2[ccc] * s2[ccc] * rw[ccc * 3 + tid];
    route[tid] = sigmoidf_(z);
  }
  __syncthreads();
  if (tid < 64) Sp[tid] = S_raw[((size_t)b * 9 + tap) * 64 + tid] * s2[tid];
  __syncthreads();

  float acc = 0.f;
#pragma unroll
  for (int e = 0; e < 3; ++e) {
    float m = 0.f;
    const float* E = experts3 + ((size_t)(e * 9 + tap) * 64) * 128 + tid;
#pragma unroll 16
    for (int ccc = 0; ccc < 64; ++ccc) m = fmaf(E[(size_t)ccc * 128], Sp[ccc], m);
    acc += route[e] * m;
  }
  const float inv = gamma[tid] * rsqrtf(bnvar[tid] + EPSBN);
  float contrib = (acc * (1.0f / 1024.0f)) * inv;
  if (tap == 4) contrib += beta[tid] - bnmean[tid] * inv;
  atomicAdd(&out[b * 128 + tid], contrib);
}

extern "C" void kernel_launch(void* const* d_in, const int* in_sizes, int n_in,
                              void* d_out, int out_size, void* d_ws, size_t ws_size,
                              hipStream_t stream) {
  const float* x        = (const float*)d_in[0];
  const float* experts1 = (const float*)d_in[1];
  const float* rw1      = (const float*)d_in[2];
  const float* rb1      = (const float*)d_in[3];
  const float* g1  = (const float*)d_in[4];
  const float* be1 = (const float*)d_in[5];
  const float* mu1 = (const float*)d_in[6];
  const float* va1 = (const float*)d_in[7];
  const float* sw1a = (const float*)d_in[8];
  const float* sw1b = (const float*)d_in[9];
  const float* experts2 = (const float*)d_in[10];
  const float* rw2 = (const float*)d_in[11];
  const float* rb2 = (const float*)d_in[12];
  const float* g2  = (const float*)d_in[13];
  const float* be2 = (const float*)d_in[14];
  const float* mu2 = (const float*)d_in[15];
  const float* va2 = (const float*)d_in[16];
  const float* sw2a = (const float*)d_in[17];
  const float* sw2b = (const float*)d_in[18];
  const float* experts3 = (const float*)d_in[19];
  const float* rw3 = (const float*)d_in[20];
  const float* rb3 = (const float*)d_in[21];
  const float* g3  = (const float*)d_in[22];
  const float* be3 = (const float*)d_in[23];
  const float* mu3 = (const float*)d_in[24];
  const float* va3 = (const float*)d_in[25];
  float* out = (float*)d_out;
  float* ws = (float*)d_ws;

  // workspace layout (float offsets, all 16B-aligned):
  float* meanx_raw = ws;                         // 384
  float* k1p       = ws + 384;                   // 110592
  float* mean1_raw = ws + 110976;                // 2048
  ushort_t* k2pb   = (ushort_t*)(ws + 113024);   // 1,179,648 ushorts = 589,824 floats
  float* S_raw     = ws + 702848;                // 36864
  ushort_t* p1b    = (ushort_t*)(ws + 739712);   // 8,388,608 ushorts = 4,194,304 floats
  float* p2        = ws + 4934016;               // 4,194,304 floats
  // end: 9,128,320 floats = 36.5 MB

  hipMemsetAsync(meanx_raw, 0, 384 * sizeof(float), stream);
  hipMemsetAsync(d_out, 0, (size_t)out_size * sizeof(float), stream);

  hipLaunchKernelGGL(k_mean_x, dim3(256), dim3(256), 0, stream, x, meanx_raw);
  hipLaunchKernelGGL(k_buildk1, dim3(64), dim3(256), 0, stream,
                     meanx_raw, experts1, rw1, rb1, g1, va1, k1p);
  hipLaunchKernelGGL(k_conv1, dim3(1024), dim3(256), 0, stream,
                     x, k1p, g1, be1, mu1, va1, p1b);
  hipLaunchKernelGGL(k_mean1, dim3(64), dim3(256), 0, stream, p1b, mean1_raw);
  hipLaunchKernelGGL(k_buildk2, dim3(64), dim3(256), 0, stream,
                     mean1_raw, experts2, rw2, rb2, sw1a, sw1b, g2, va2, k2pb);
  hipLaunchKernelGGL(k_conv2, dim3(2048), dim3(256), 0, stream,
                     p1b, k2pb, g2, be2, mu2, va2, p2);
  hipLaunchKernelGGL(k_s3, dim3(1024), dim3(256), 0, stream, p2, S_raw);
  hipLaunchKernelGGL(k_final, dim3(576), dim3(128), 0, stream,
                     S_raw, experts3, rw3, rb3, sw2a, sw2b, g3, be3, mu3, va3, out);
}

// Round 3
// 221.783 us; speedup vs baseline: 1.5074x; 1.1068x over previous
//
#include <hip/hip_runtime.h>

#define EPSBN 1e-3f

typedef unsigned short ushort_t;
typedef __attribute__((ext_vector_type(8))) short bf8;   // 8 bf16 = 4 VGPRs
typedef __attribute__((ext_vector_type(4))) float f4;

__device__ __forceinline__ float sigmoidf_(float z) {
  return 1.0f / (1.0f + expf(-z));
}

__device__ __forceinline__ ushort_t f2bf(float x) {  // RTNE
  union { float f; unsigned u; } v; v.f = x;
  unsigned r = (v.u + 0x7fffu + ((v.u >> 16) & 1u)) >> 16;
  return (ushort_t)r;
}

__device__ __forceinline__ float bfbits2f(unsigned hi_bits) {
  union { unsigned u; float f; } v; v.u = hi_bits;
  return v.f;
}

// ---------------- K: partial channel sums of x (256 blocks = b*4+q) ------------
__global__ void k_mean_x(const float* __restrict__ x, float* __restrict__ part) {
  const int b = blockIdx.x >> 2;
  const int q = blockIdx.x & 3;
  const int tid = threadIdx.x;
  float acc[6] = {0.f, 0.f, 0.f, 0.f, 0.f, 0.f};
  const float* xb = x + (size_t)b * (128 * 128 * 6);
  for (int i = 0; i < 16; ++i) {
    const int p = q * 4096 + i * 256 + tid;
    const float* px = xb + (size_t)p * 6;
#pragma unroll
    for (int c = 0; c < 6; ++c) acc[c] += px[c];
  }
#pragma unroll
  for (int c = 0; c < 6; ++c)
    for (int off = 32; off > 0; off >>= 1) acc[c] += __shfl_down(acc[c], off, 64);
  __shared__ float red[4][6];
  const int lane = tid & 63, w = tid >> 6;
  if (lane == 0) {
#pragma unroll
    for (int c = 0; c < 6; ++c) red[w][c] = acc[c];
  }
  __syncthreads();
  if (tid < 6) {
    part[blockIdx.x * 6 + tid] = red[0][tid] + red[1][tid] + red[2][tid] + red[3][tid];
  }
}

// ------------- K: route1 + build conv1 B-fragments bf16 (BN inv folded) --------
// k1b layout per batch: s = ((ky*2+nt)*64 + lane)*8 + j ; lane=(lg*16+lx)
// value = W'[kx=lg][ci=j][co=nt*16+lx], zero for lg==3 or j>=6.
__global__ void k_buildk1(const float* __restrict__ part,
                          const float* __restrict__ experts1,
                          const float* __restrict__ rw, const float* __restrict__ rb,
                          const float* __restrict__ gamma, const float* __restrict__ var,
                          ushort_t* __restrict__ k1b) {
  const int b = blockIdx.x;
  const int tid = threadIdx.x;
  __shared__ float route[3];
  if (tid < 3) {
    float z = rb[tid];
    for (int c = 0; c < 6; ++c) {
      const float s = part[(b * 4 + 0) * 6 + c] + part[(b * 4 + 1) * 6 + c] +
                      part[(b * 4 + 2) * 6 + c] + part[(b * 4 + 3) * 6 + c];
      z += (s * (1.0f / 16384.0f)) * rw[c * 3 + tid];
    }
    route[tid] = sigmoidf_(z);
  }
  __syncthreads();
  const float r0 = route[0], r1 = route[1], r2 = route[2];
  for (int s = tid; s < 3072; s += 256) {
    const int j = s & 7;
    const int lane = (s >> 3) & 63;
    const int nt = (s >> 9) & 1;
    const int ky = s >> 10;
    const int lx = lane & 15, lg = lane >> 4;
    const int co = nt * 16 + lx;
    float val = 0.f;
    if (lg < 3 && j < 6) {
      const int idx = ((ky * 3 + lg) * 6 + j) * 32 + co;
      const float v = r0 * experts1[idx] + r1 * experts1[1728 + idx] + r2 * experts1[3456 + idx];
      val = v * gamma[co] * rsqrtf(var[co] + EPSBN);
    }
    k1b[(size_t)b * 3072 + s] = f2bf(val);
  }
}

// ------------- K: conv1 via MFMA + bias + relu + maxpool2 ----------------------
// grid: 64 b x 4 row-tiles x 2 col-tiles = 512 blocks; tile = 32 rows x 64 cols.
// patch LDS [34 rows][68 px][8 ci-padded] bf16. Output p1b [b][64][64][32] bf16.
__global__ __launch_bounds__(256)
void k_conv1(const float* __restrict__ x, const ushort_t* __restrict__ k1b,
             const float* __restrict__ gamma, const float* __restrict__ beta,
             const float* __restrict__ bnmean, const float* __restrict__ bnvar,
             ushort_t* __restrict__ p1b) {
  const int bid = blockIdx.x;
  const int b = bid >> 3;
  const int tyi = (bid >> 1) & 3;
  const int txi = bid & 1;
  __shared__ __align__(16) ushort_t patch[34 * 68 * 8];  // 36,992 B
  const int tid = threadIdx.x;
  const float* xb = x + (size_t)b * (128 * 128 * 6);

  for (int v = tid; v < 34 * 68; v += 256) {
    const int ry = v / 68, p = v - ry * 68;
    const int gy = tyi * 32 - 1 + ry, gx = txi * 64 - 1 + p;
    uint4 u = make_uint4(0u, 0u, 0u, 0u);
    if (((unsigned)gy < 128u) && ((unsigned)gx < 128u)) {
      const float* s = xb + ((size_t)(gy * 128 + gx)) * 6;
      const float2 a0 = *(const float2*)s;
      const float2 a1 = *(const float2*)(s + 2);
      const float2 a2 = *(const float2*)(s + 4);
      u.x = (unsigned)f2bf(a0.x) | ((unsigned)f2bf(a0.y) << 16);
      u.y = (unsigned)f2bf(a1.x) | ((unsigned)f2bf(a1.y) << 16);
      u.z = (unsigned)f2bf(a2.x) | ((unsigned)f2bf(a2.y) << 16);
      u.w = 0u;
    }
    *(uint4*)(patch + (size_t)v * 8) = u;
  }

  const int w = tid >> 6;
  const int lane = tid & 63;
  const int lx = lane & 15, lg = lane >> 4;

  // B fragments: 6 coalesced 16B loads, reused for all tiles
  bf8 Bf[3][2];
#pragma unroll
  for (int ky = 0; ky < 3; ++ky)
#pragma unroll
    for (int nt = 0; nt < 2; ++nt)
      Bf[ky][nt] = *(const bf8*)(k1b + (size_t)b * 3072 + ((size_t)((ky * 2 + nt) * 64 + lane)) * 8);

  // BN constants for this lane's two output channels
  const int co0 = lx, co1 = 16 + lx;
  const float inv0 = gamma[co0] * rsqrtf(bnvar[co0] + EPSBN);
  const float bias0 = beta[co0] - bnmean[co0] * inv0;
  const float inv1 = gamma[co1] * rsqrtf(bnvar[co1] + EPSBN);
  const float bias1 = beta[co1] - bnmean[co1] * inv1;

  __syncthreads();

#pragma unroll
  for (int rp = 0; rp < 4; ++rp) {
    const int y0 = w * 8 + rp * 2;
    const int prow = tyi * 16 + w * 4 + rp;
#pragma unroll
    for (int xt = 0; xt < 4; ++xt) {
      bf8 Af[4];
#pragma unroll
      for (int ri = 0; ri < 4; ++ri)
        Af[ri] = *(const bf8*)(patch + ((size_t)(y0 + ri) * 68 + xt * 16 + lx + lg) * 8);
      f4 acc0[2], acc1[2];
#pragma unroll
      for (int nt = 0; nt < 2; ++nt) {
        acc0[nt] = (f4){0.f, 0.f, 0.f, 0.f};
        acc1[nt] = (f4){0.f, 0.f, 0.f, 0.f};
      }
#pragma unroll
      for (int ky = 0; ky < 3; ++ky) {
#pragma unroll
        for (int nt = 0; nt < 2; ++nt) {
          acc0[nt] = __builtin_amdgcn_mfma_f32_16x16x32_bf16(Af[ky], Bf[ky][nt], acc0[nt], 0, 0, 0);
          acc1[nt] = __builtin_amdgcn_mfma_f32_16x16x32_bf16(Af[ky + 1], Bf[ky][nt], acc1[nt], 0, 0, 0);
        }
      }
#pragma unroll
      for (int nt = 0; nt < 2; ++nt) {
        const float inv = nt ? inv1 : inv0;
        const float bias = nt ? bias1 : bias0;
        const int co = nt * 16 + lx;
#pragma unroll
        for (int q = 0; q < 2; ++q) {
          const float m0 = fmaxf(acc0[nt][2 * q] + bias, 0.f);
          const float m1 = fmaxf(acc0[nt][2 * q + 1] + bias, 0.f);
          const float m2 = fmaxf(acc1[nt][2 * q] + bias, 0.f);
          const float m3 = fmaxf(acc1[nt][2 * q + 1] + bias, 0.f);
          const float mx = fmaxf(fmaxf(m0, m1), fmaxf(m2, m3));
          const int pcol = txi * 32 + xt * 8 + lg * 2 + q;
          p1b[(((size_t)b * 64 + prow) * 64 + pcol) * 32 + co] = f2bf(mx);
        }
      }
    }
  }
}

// ------------- K: partial channel sums of p1b (256 blocks = b*4+q) -------------
__global__ void k_mean1(const ushort_t* __restrict__ p1b, float* __restrict__ part) {
  const int b = blockIdx.x >> 2;
  const int q = blockIdx.x & 3;
  const int tid = threadIdx.x;
  const int oct = tid & 3, row0 = tid >> 2;
  const ushort_t* base = p1b + (size_t)b * 131072;
  float s[8] = {0.f, 0.f, 0.f, 0.f, 0.f, 0.f, 0.f, 0.f};
  for (int k = 0; k < 16; ++k) {
    const int pos = q * 1024 + (k << 6) + row0;
    const uint4 u = *(const uint4*)(base + (size_t)pos * 32 + oct * 8);
    const unsigned uu[4] = {u.x, u.y, u.z, u.w};
#pragma unroll
    for (int j = 0; j < 4; ++j) {
      s[2 * j]     += bfbits2f(uu[j] << 16);
      s[2 * j + 1] += bfbits2f(uu[j] & 0xffff0000u);
    }
  }
  __shared__ float red[256][8];
#pragma unroll
  for (int j = 0; j < 8; ++j) red[tid][j] = s[j];
  __syncthreads();
  if (tid < 32) {
    float t = 0.f;
    const int o = tid >> 3, j = tid & 7;
    for (int r = 0; r < 64; ++r) t += red[r * 4 + o][j];
    part[blockIdx.x * 32 + tid] = t;
  }
}

// ------------- K: SE1 + route2 + build k2' bf16 [b][tap][co][ci] ---------------
__global__ void k_buildk2(const float* __restrict__ part,
                          const float* __restrict__ experts2,
                          const float* __restrict__ rw, const float* __restrict__ rb,
                          const float* __restrict__ w1, const float* __restrict__ w2,
                          const float* __restrict__ gamma, const float* __restrict__ var,
                          ushort_t* __restrict__ k2pb) {
  const int b = blockIdx.x, tid = threadIdx.x;
  __shared__ float m1[32], h[2], s1[32], route[3];
  if (tid < 32) {
    const float s = part[(b * 4 + 0) * 32 + tid] + part[(b * 4 + 1) * 32 + tid] +
                    part[(b * 4 + 2) * 32 + tid] + part[(b * 4 + 3) * 32 + tid];
    m1[tid] = s * (1.0f / 4096.0f);
  }
  __syncthreads();
  if (tid < 2) {
    float z = 0.f;
    for (int c = 0; c < 32; ++c) z += m1[c] * w1[c * 2 + tid];
    h[tid] = fmaxf(z, 0.f);
  }
  __syncthreads();
  if (tid < 32) s1[tid] = sigmoidf_(h[0] * w2[tid] + h[1] * w2[32 + tid]);
  __syncthreads();
  if (tid < 3) {
    float z = rb[tid];
    for (int c = 0; c < 32; ++c) z += m1[c] * s1[c] * rw[c * 3 + tid];
    route[tid] = sigmoidf_(z);
  }
  __syncthreads();
  const float r0 = route[0], r1 = route[1], r2 = route[2];
  for (int t = tid; t < 18432; t += 256) {
    const int co = t & 63;
    const int ci = (t >> 6) & 31;
    const int tap = t >> 11;
    const float inv = gamma[co] * rsqrtf(var[co] + EPSBN);
    const float v = r0 * experts2[t] + r1 * experts2[18432 + t] + r2 * experts2[2 * 18432 + t];
    k2pb[(size_t)b * 18432 + ((size_t)tap * 64 + co) * 32 + ci] = f2bf(v * s1[ci] * inv);
  }
}

// ------------- K: conv2 via MFMA implicit GEMM + bias + relu + maxpool2 --------
__global__ __launch_bounds__(256)
void k_conv2(const ushort_t* __restrict__ p1b, const ushort_t* __restrict__ k2pb,
             const float* __restrict__ gamma, const float* __restrict__ beta,
             const float* __restrict__ bnmean, const float* __restrict__ bnvar,
             float* __restrict__ p2) {
  const int bi = blockIdx.x;
  const int b = bi >> 5;
  const int tile = (bi >> 1) & 15;
  const int cog = bi & 1;
  const int ty = tile >> 2, tx = tile & 3;
  __shared__ __align__(16) short smem[24480];
  short* As = smem;
  short* Bs = smem + 12960;
  const int tid = threadIdx.x;

  const ushort_t* pb = p1b + (size_t)b * 131072;
  for (int v = tid; v < 1296; v += 256) {
    const int cell = v >> 2, part = v & 3;
    const int ly = cell / 18, lx2 = cell - ly * 18;
    const int gy = ty * 16 - 1 + ly, gx = tx * 16 - 1 + lx2;
    uint4 d = make_uint4(0u, 0u, 0u, 0u);
    if (((unsigned)gy < 64u) && ((unsigned)gx < 64u))
      d = *(const uint4*)(pb + (((size_t)gy << 6) + gx) * 32 + part * 8);
    *(uint4*)(As + (ly * 18 + lx2) * 40 + part * 8) = d;
  }
  for (int v = tid; v < 1152; v += 256) {
    const int r = v >> 2, part = v & 3;
    const int t = r >> 5, n = r & 31;
    const uint4 d = *(const uint4*)(k2pb + (size_t)b * 18432 +
                                    ((size_t)(t * 64 + cog * 32 + n)) * 32 + part * 8);
    *(uint4*)(Bs + r * 40 + part * 8) = d;
  }
  __syncthreads();

  const int w = tid >> 6;
  const int lane = tid & 63;
  const int lx = lane & 15, lg = lane >> 4;

  f4 acc[4][2];
#pragma unroll
  for (int mt = 0; mt < 4; ++mt)
#pragma unroll
    for (int nt = 0; nt < 2; ++nt)
      acc[mt][nt] = (f4){0.f, 0.f, 0.f, 0.f};

#pragma unroll
  for (int t = 0; t < 9; ++t) {
    const int ky = t / 3, kx = t - 3 * (t / 3);
    bf8 Bf0 = *(const bf8*)(Bs + ((t << 5) + lx) * 40 + (lg << 3));
    bf8 Bf1 = *(const bf8*)(Bs + ((t << 5) + 16 + lx) * 40 + (lg << 3));
#pragma unroll
    for (int mt = 0; mt < 4; ++mt) {
      const int y = 4 * w + mt + ky;
      const bf8 Af = *(const bf8*)(As + (y * 18 + lx + kx) * 40 + (lg << 3));
      acc[mt][0] = __builtin_amdgcn_mfma_f32_16x16x32_bf16(Af, Bf0, acc[mt][0], 0, 0, 0);
      acc[mt][1] = __builtin_amdgcn_mfma_f32_16x16x32_bf16(Af, Bf1, acc[mt][1], 0, 0, 0);
    }
  }

#pragma unroll
  for (int nt = 0; nt < 2; ++nt) {
    const int co = cog * 32 + nt * 16 + lx;
    const float inv = gamma[co] * rsqrtf(bnvar[co] + EPSBN);
    const float bias = beta[co] - bnmean[co] * inv;
#pragma unroll
    for (int half = 0; half < 2; ++half) {
      const int prow = ty * 8 + 2 * w + half;
#pragma unroll
      for (int q = 0; q < 2; ++q) {
        const float m0 = fmaxf(acc[2 * half][nt][2 * q] + bias, 0.f);
        const float m1 = fmaxf(acc[2 * half][nt][2 * q + 1] + bias, 0.f);
        const float m2 = fmaxf(acc[2 * half + 1][nt][2 * q] + bias, 0.f);
        const float m3 = fmaxf(acc[2 * half + 1][nt][2 * q + 1] + bias, 0.f);
        const float mx = fmaxf(fmaxf(m0, m1), fmaxf(m2, m3));
        p2[(((size_t)b * 64 + co) * 32 + prow) * 32 + tx * 8 + 2 * lg + q] = mx;
      }
    }
  }
}

// ------------- K: stage-3 shifted plane sums S[b][9][ci] from p2 ---------------
__global__ void k_s3(const float* __restrict__ p2, float* __restrict__ S_raw) {
  const int b = blockIdx.x >> 4, cb = blockIdx.x & 15;
  const int w = threadIdx.x >> 6, lane = threadIdx.x & 63;
  const int ci = cb * 4 + w;
  const float* plane = p2 + ((size_t)b * 64 + ci) * 1024;
  float t = 0.f, r0 = 0.f, rl = 0.f, c0 = 0.f, cl = 0.f;
  float k00 = 0.f, k01 = 0.f, k10 = 0.f, k11 = 0.f;
  const int c = lane & 31;
#pragma unroll
  for (int i = 0; i < 16; ++i) {
    const int idx = i * 64 + lane;
    const float v = plane[idx];
    const int r = idx >> 5;
    t += v;
    if (r == 0) r0 += v;
    if (r == 31) rl += v;
    if (c == 0) c0 += v;
    if (c == 31) cl += v;
    if (r == 0 && c == 0) k00 = v;
    if (r == 0 && c == 31) k01 = v;
    if (r == 31 && c == 0) k10 = v;
    if (r == 31 && c == 31) k11 = v;
  }
  for (int off = 32; off > 0; off >>= 1) {
    t += __shfl_down(t, off, 64);
    r0 += __shfl_down(r0, off, 64);
    rl += __shfl_down(rl, off, 64);
    c0 += __shfl_down(c0, off, 64);
    cl += __shfl_down(cl, off, 64);
    k00 += __shfl_down(k00, off, 64);
    k01 += __shfl_down(k01, off, 64);
    k10 += __shfl_down(k10, off, 64);
    k11 += __shfl_down(k11, off, 64);
  }
  if (lane == 0) {
    const float A[3] = {rl, 0.f, r0};
    const float B[3] = {cl, 0.f, c0};
    const float AB[3][3] = {{k11, 0.f, k10}, {0.f, 0.f, 0.f}, {k01, 0.f, k00}};
#pragma unroll
    for (int ky = 0; ky < 3; ++ky)
#pragma unroll
      for (int kx = 0; kx < 3; ++kx)
        S_raw[((size_t)b * 9 + ky * 3 + kx) * 64 + ci] = t - A[ky] - B[kx] + AB[ky][kx];
  }
}

// ------------- K: SE2 + route3 + stage-3 contraction + BN3 (per-batch block) ---
__global__ void k_final(const float* __restrict__ S_raw, const float* __restrict__ experts3,
                        const float* __restrict__ rw, const float* __restrict__ rb,
                        const float* __restrict__ w1, const float* __restrict__ w2,
                        const float* __restrict__ gamma, const float* __restrict__ beta,
                        const float* __restrict__ bnmean, const float* __restrict__ bnvar,
                        float* __restrict__ out) {
  const int b = blockIdx.x;
  const int tid = threadIdx.x;
  __shared__ float m2[64], h[4], s2[64], route[3], Sp[9][64], redf[2][128];
  if (tid < 64) m2[tid] = S_raw[((size_t)b * 9 + 4) * 64 + tid] * (1.0f / 1024.0f);
  __syncthreads();
  if (tid < 4) {
    float z = 0.f;
    for (int c = 0; c < 64; ++c) z += m2[c] * w1[c * 4 + tid];
    h[tid] = fmaxf(z, 0.f);
  }
  __syncthreads();
  if (tid < 64) {
    float z = 0.f;
#pragma unroll
    for (int j = 0; j < 4; ++j) z += h[j] * w2[j * 64 + tid];
    s2[tid] = sigmoidf_(z);
  }
  __syncthreads();
  if (tid < 3) {
    float z = rb[tid];
    for (int c = 0; c < 64; ++c) z += m2[c] * s2[c] * rw[c * 3 + tid];
    route[tid] = sigmoidf_(z);
  }
  __syncthreads();
  for (int v = tid; v < 576; v += 256) {
    const int tap = v >> 6, ci = v & 63;
    Sp[tap][ci] = S_raw[((size_t)b * 9 + tap) * 64 + ci] * s2[ci];
  }
  __syncthreads();

  const int co = tid & 127;
  const int hf = tid >> 7;
  const int tap_lo = hf ? 5 : 0;
  const int tap_hi = hf ? 9 : 5;
  float acc = 0.f;
#pragma unroll
  for (int e = 0; e < 3; ++e) {
    float m = 0.f;
    for (int tap = tap_lo; tap < tap_hi; ++tap) {
      const float* E = experts3 + ((size_t)(e * 9 + tap) * 64) * 128 + co;
#pragma unroll 16
      for (int ci = 0; ci < 64; ++ci) m = fmaf(E[(size_t)ci * 128], Sp[tap][ci], m);
    }
    acc += route[e] * m;
  }
  redf[hf][co] = acc;
  __syncthreads();
  if (tid < 128) {
    const float total = redf[0][tid] + redf[1][tid];
    const float inv = gamma[tid] * rsqrtf(bnvar[tid] + EPSBN);
    out[(size_t)b * 128 + tid] = total * (1.0f / 1024.0f) * inv + (beta[tid] - bnmean[tid] * inv);
  }
}

extern "C" void kernel_launch(void* const* d_in, const int* in_sizes, int n_in,
                              void* d_out, int out_size, void* d_ws, size_t ws_size,
                              hipStream_t stream) {
  const float* x        = (const float*)d_in[0];
  const float* experts1 = (const float*)d_in[1];
  const float* rw1      = (const float*)d_in[2];
  const float* rb1      = (const float*)d_in[3];
  const float* g1  = (const float*)d_in[4];
  const float* be1 = (const float*)d_in[5];
  const float* mu1 = (const float*)d_in[6];
  const float* va1 = (const float*)d_in[7];
  const float* sw1a = (const float*)d_in[8];
  const float* sw1b = (const float*)d_in[9];
  const float* experts2 = (const float*)d_in[10];
  const float* rw2 = (const float*)d_in[11];
  const float* rb2 = (const float*)d_in[12];
  const float* g2  = (const float*)d_in[13];
  const float* be2 = (const float*)d_in[14];
  const float* mu2 = (const float*)d_in[15];
  const float* va2 = (const float*)d_in[16];
  const float* sw2a = (const float*)d_in[17];
  const float* sw2b = (const float*)d_in[18];
  const float* experts3 = (const float*)d_in[19];
  const float* rw3 = (const float*)d_in[20];
  const float* rb3 = (const float*)d_in[21];
  const float* g3  = (const float*)d_in[22];
  const float* be3 = (const float*)d_in[23];
  const float* mu3 = (const float*)d_in[24];
  const float* va3 = (const float*)d_in[25];
  float* out = (float*)d_out;
  float* ws = (float*)d_ws;

  // workspace layout (float offsets, all 16B-aligned):
  float* meanx_part = ws;                          // 1536
  float* mean1_part = ws + 1536;                   // 8192
  ushort_t* k1b     = (ushort_t*)(ws + 9728);      // 196,608 shorts = 98,304 fl
  ushort_t* k2pb    = (ushort_t*)(ws + 108032);    // 1,179,648 shorts = 589,824 fl
  float* S_raw      = ws + 697856;                 // 36,864
  ushort_t* p1b     = (ushort_t*)(ws + 734720);    // 8,388,608 shorts = 4,194,304 fl
  float* p2         = ws + 4929024;                // 4,194,304 fl
  // end: 9,123,328 floats = 36.5 MB

  hipLaunchKernelGGL(k_mean_x, dim3(256), dim3(256), 0, stream, x, meanx_part);
  hipLaunchKernelGGL(k_buildk1, dim3(64), dim3(256), 0, stream,
                     meanx_part, experts1, rw1, rb1, g1, va1, k1b);
  hipLaunchKernelGGL(k_conv1, dim3(512), dim3(256), 0, stream,
                     x, k1b, g1, be1, mu1, va1, p1b);
  hipLaunchKernelGGL(k_mean1, dim3(256), dim3(256), 0, stream, p1b, mean1_part);
  hipLaunchKernelGGL(k_buildk2, dim3(64), dim3(256), 0, stream,
                     mean1_part, experts2, rw2, rb2, sw1a, sw1b, g2, va2, k2pb);
  hipLaunchKernelGGL(k_conv2, dim3(2048), dim3(256), 0, stream,
                     p1b, k2pb, g2, be2, mu2, va2, p2);
  hipLaunchKernelGGL(k_s3, dim3(1024), dim3(256), 0, stream, p2, S_raw);
  hipLaunchKernelGGL(k_final, dim3(64), dim3(256), 0, stream,
                     S_raw, experts3, rw3, rb3, sw2a, sw2b, g3, be3, mu3, va3, out);
}

// Round 4
// 207.341 us; speedup vs baseline: 1.6124x; 1.0697x over previous
//
#include <hip/hip_runtime.h>

#define EPSBN 1e-3f

typedef unsigned short ushort_t;
typedef __attribute__((ext_vector_type(8))) short bf8;   // 8 bf16 = 4 VGPRs
typedef __attribute__((ext_vector_type(4))) float f4;

__device__ __forceinline__ float sigmoidf_(float z) {
  return 1.0f / (1.0f + expf(-z));
}

__device__ __forceinline__ ushort_t f2bf(float x) {  // RTNE
  union { float f; unsigned u; } v; v.f = x;
  unsigned r = (v.u + 0x7fffu + ((v.u >> 16) & 1u)) >> 16;
  return (ushort_t)r;
}

// ---------------- K: partial channel sums of x (256 blocks = b*4+q) ------------
__global__ void k_mean_x(const float* __restrict__ x, float* __restrict__ part) {
  const int b = blockIdx.x >> 2;
  const int q = blockIdx.x & 3;
  const int tid = threadIdx.x;
  float acc[6] = {0.f, 0.f, 0.f, 0.f, 0.f, 0.f};
  const float* xb = x + (size_t)b * (128 * 128 * 6);
  for (int i = 0; i < 16; ++i) {
    const int p = q * 4096 + i * 256 + tid;
    const float* px = xb + (size_t)p * 6;
#pragma unroll
    for (int c = 0; c < 6; ++c) acc[c] += px[c];
  }
#pragma unroll
  for (int c = 0; c < 6; ++c)
    for (int off = 32; off > 0; off >>= 1) acc[c] += __shfl_down(acc[c], off, 64);
  __shared__ float red[4][6];
  const int lane = tid & 63, w = tid >> 6;
  if (lane == 0) {
#pragma unroll
    for (int c = 0; c < 6; ++c) red[w][c] = acc[c];
  }
  __syncthreads();
  if (tid < 6) {
    part[blockIdx.x * 6 + tid] = red[0][tid] + red[1][tid] + red[2][tid] + red[3][tid];
  }
}

// ------------- K: route1 + build conv1 B-fragments bf16 (BN inv folded) --------
__global__ void k_buildk1(const float* __restrict__ part,
                          const float* __restrict__ experts1,
                          const float* __restrict__ rw, const float* __restrict__ rb,
                          const float* __restrict__ gamma, const float* __restrict__ var,
                          ushort_t* __restrict__ k1b) {
  const int b = blockIdx.x;
  const int tid = threadIdx.x;
  __shared__ float route[3];
  if (tid < 3) {
    float z = rb[tid];
    for (int c = 0; c < 6; ++c) {
      const float s = part[(b * 4 + 0) * 6 + c] + part[(b * 4 + 1) * 6 + c] +
                      part[(b * 4 + 2) * 6 + c] + part[(b * 4 + 3) * 6 + c];
      z += (s * (1.0f / 16384.0f)) * rw[c * 3 + tid];
    }
    route[tid] = sigmoidf_(z);
  }
  __syncthreads();
  const float r0 = route[0], r1 = route[1], r2 = route[2];
  for (int s = tid; s < 3072; s += 256) {
    const int j = s & 7;
    const int lane = (s >> 3) & 63;
    const int nt = (s >> 9) & 1;
    const int ky = s >> 10;
    const int lx = lane & 15, lg = lane >> 4;
    const int co = nt * 16 + lx;
    float val = 0.f;
    if (lg < 3 && j < 6) {
      const int idx = ((ky * 3 + lg) * 6 + j) * 32 + co;
      const float v = r0 * experts1[idx] + r1 * experts1[1728 + idx] + r2 * experts1[3456 + idx];
      val = v * gamma[co] * rsqrtf(var[co] + EPSBN);
    }
    k1b[(size_t)b * 3072 + s] = f2bf(val);
  }
}

// ------------- K: conv1 via MFMA + bias + relu + maxpool2 + mean1 partials -----
// grid: 64 b x 4 row-tiles x 2 col-tiles = 512 blocks.
// Output p1b [b][64][64][32] bf16, part_m1[bid][32] fp32 partial channel sums.
__global__ __launch_bounds__(256)
void k_conv1(const float* __restrict__ x, const ushort_t* __restrict__ k1b,
             const float* __restrict__ gamma, const float* __restrict__ beta,
             const float* __restrict__ bnmean, const float* __restrict__ bnvar,
             ushort_t* __restrict__ p1b, float* __restrict__ part_m1) {
  const int bid = blockIdx.x;
  const int b = bid >> 3;
  const int tyi = (bid >> 1) & 3;
  const int txi = bid & 1;
  __shared__ __align__(16) ushort_t patch[34 * 68 * 8];  // 36,992 B
  __shared__ float mred[4][32];
  const int tid = threadIdx.x;
  const float* xb = x + (size_t)b * (128 * 128 * 6);

  for (int v = tid; v < 34 * 68; v += 256) {
    const int ry = v / 68, p = v - ry * 68;
    const int gy = tyi * 32 - 1 + ry, gx = txi * 64 - 1 + p;
    uint4 u = make_uint4(0u, 0u, 0u, 0u);
    if (((unsigned)gy < 128u) && ((unsigned)gx < 128u)) {
      const float* s = xb + ((size_t)(gy * 128 + gx)) * 6;
      const float2 a0 = *(const float2*)s;
      const float2 a1 = *(const float2*)(s + 2);
      const float2 a2 = *(const float2*)(s + 4);
      u.x = (unsigned)f2bf(a0.x) | ((unsigned)f2bf(a0.y) << 16);
      u.y = (unsigned)f2bf(a1.x) | ((unsigned)f2bf(a1.y) << 16);
      u.z = (unsigned)f2bf(a2.x) | ((unsigned)f2bf(a2.y) << 16);
      u.w = 0u;
    }
    *(uint4*)(patch + (size_t)v * 8) = u;
  }

  const int w = tid >> 6;
  const int lane = tid & 63;
  const int lx = lane & 15, lg = lane >> 4;

  bf8 Bf[3][2];
#pragma unroll
  for (int ky = 0; ky < 3; ++ky)
#pragma unroll
    for (int nt = 0; nt < 2; ++nt)
      Bf[ky][nt] = *(const bf8*)(k1b + (size_t)b * 3072 + ((size_t)((ky * 2 + nt) * 64 + lane)) * 8);

  const int co0 = lx, co1 = 16 + lx;
  const float inv0 = gamma[co0] * rsqrtf(bnvar[co0] + EPSBN);
  const float bias0 = beta[co0] - bnmean[co0] * inv0;
  const float inv1 = gamma[co1] * rsqrtf(bnvar[co1] + EPSBN);
  const float bias1 = beta[co1] - bnmean[co1] * inv1;

  __syncthreads();

  float msum0 = 0.f, msum1 = 0.f;

#pragma unroll
  for (int rp = 0; rp < 4; ++rp) {
    const int y0 = w * 8 + rp * 2;
    const int prow = tyi * 16 + w * 4 + rp;
#pragma unroll
    for (int xt = 0; xt < 4; ++xt) {
      bf8 Af[4];
#pragma unroll
      for (int ri = 0; ri < 4; ++ri)
        Af[ri] = *(const bf8*)(patch + ((size_t)(y0 + ri) * 68 + xt * 16 + lx + lg) * 8);
      f4 acc0[2], acc1[2];
#pragma unroll
      for (int nt = 0; nt < 2; ++nt) {
        acc0[nt] = (f4){0.f, 0.f, 0.f, 0.f};
        acc1[nt] = (f4){0.f, 0.f, 0.f, 0.f};
      }
#pragma unroll
      for (int ky = 0; ky < 3; ++ky) {
#pragma unroll
        for (int nt = 0; nt < 2; ++nt) {
          acc0[nt] = __builtin_amdgcn_mfma_f32_16x16x32_bf16(Af[ky], Bf[ky][nt], acc0[nt], 0, 0, 0);
          acc1[nt] = __builtin_amdgcn_mfma_f32_16x16x32_bf16(Af[ky + 1], Bf[ky][nt], acc1[nt], 0, 0, 0);
        }
      }
#pragma unroll
      for (int nt = 0; nt < 2; ++nt) {
        const float inv = nt ? inv1 : inv0;
        const float bias = nt ? bias1 : bias0;
        const int co = nt * 16 + lx;
#pragma unroll
        for (int q = 0; q < 2; ++q) {
          const float m0 = fmaxf(acc0[nt][2 * q] + bias, 0.f);
          const float m1 = fmaxf(acc0[nt][2 * q + 1] + bias, 0.f);
          const float m2 = fmaxf(acc1[nt][2 * q] + bias, 0.f);
          const float m3 = fmaxf(acc1[nt][2 * q + 1] + bias, 0.f);
          const float mx = fmaxf(fmaxf(m0, m1), fmaxf(m2, m3));
          if (nt) msum1 += mx; else msum0 += mx;
          const int pcol = txi * 32 + xt * 8 + lg * 2 + q;
          p1b[(((size_t)b * 64 + prow) * 64 + pcol) * 32 + co] = f2bf(mx);
        }
      }
    }
  }

  // mean1 partials: reduce over lg (lanes ^16, ^32), then over waves via LDS
  msum0 += __shfl_xor(msum0, 16, 64);
  msum0 += __shfl_xor(msum0, 32, 64);
  msum1 += __shfl_xor(msum1, 16, 64);
  msum1 += __shfl_xor(msum1, 32, 64);
  if (lg == 0) {
    mred[w][lx] = msum0;
    mred[w][16 + lx] = msum1;
  }
  __syncthreads();
  if (tid < 32) {
    part_m1[(size_t)bid * 32 + tid] =
        mred[0][tid] + mred[1][tid] + mred[2][tid] + mred[3][tid];
  }
}

// ------------- K: SE1 + route2 + build k2' bf16 [b][tap][co][ci] ---------------
__global__ void k_buildk2(const float* __restrict__ part_m1,
                          const float* __restrict__ experts2,
                          const float* __restrict__ rw, const float* __restrict__ rb,
                          const float* __restrict__ w1, const float* __restrict__ w2,
                          const float* __restrict__ gamma, const float* __restrict__ var,
                          ushort_t* __restrict__ k2pb) {
  const int b = blockIdx.x, tid = threadIdx.x;
  __shared__ float m1[32], h[2], s1[32], route[3];
  if (tid < 32) {
    float s = 0.f;
#pragma unroll
    for (int k = 0; k < 8; ++k) s += part_m1[(size_t)(b * 8 + k) * 32 + tid];
    m1[tid] = s * (1.0f / 4096.0f);
  }
  __syncthreads();
  if (tid < 2) {
    float z = 0.f;
    for (int c = 0; c < 32; ++c) z += m1[c] * w1[c * 2 + tid];
    h[tid] = fmaxf(z, 0.f);
  }
  __syncthreads();
  if (tid < 32) s1[tid] = sigmoidf_(h[0] * w2[tid] + h[1] * w2[32 + tid]);
  __syncthreads();
  if (tid < 3) {
    float z = rb[tid];
    for (int c = 0; c < 32; ++c) z += m1[c] * s1[c] * rw[c * 3 + tid];
    route[tid] = sigmoidf_(z);
  }
  __syncthreads();
  const float r0 = route[0], r1 = route[1], r2 = route[2];
  for (int t = tid; t < 18432; t += 256) {
    const int co = t & 63;
    const int ci = (t >> 6) & 31;
    const int tap = t >> 11;
    const float inv = gamma[co] * rsqrtf(var[co] + EPSBN);
    const float v = r0 * experts2[t] + r1 * experts2[18432 + t] + r2 * experts2[2 * 18432 + t];
    k2pb[(size_t)b * 18432 + ((size_t)tap * 64 + co) * 32 + ci] = f2bf(v * s1[ci] * inv);
  }
}

// ------------- K: conv2 via MFMA + bias + relu + maxpool2 + S3 tile partials ---
// grid: 64 b x 16 tiles x 2 cog. No p2 materialization: each block emits
// part_s3[bi*288 + tap*32 + co_local] = sum over its 8x8 pooled tile of values
// with (row != excluded(ky)) && (col != excluded(kx)).
__global__ __launch_bounds__(256)
void k_conv2(const ushort_t* __restrict__ p1b, const ushort_t* __restrict__ k2pb,
             const float* __restrict__ gamma, const float* __restrict__ beta,
             const float* __restrict__ bnmean, const float* __restrict__ bnvar,
             float* __restrict__ part_s3) {
  const int bi = blockIdx.x;
  const int b = bi >> 5;
  const int tile = (bi >> 1) & 15;
  const int cog = bi & 1;
  const int ty = tile >> 2, tx = tile & 3;
  __shared__ __align__(16) short smem[24480];  // As 12960 + Bs 11520 shorts
  __shared__ float sred[4][2][16][9];          // 4.6 KB
  short* As = smem;
  short* Bs = smem + 12960;
  const int tid = threadIdx.x;

  const ushort_t* pb = p1b + (size_t)b * 131072;
  for (int v = tid; v < 1296; v += 256) {
    const int cell = v >> 2, part = v & 3;
    const int ly = cell / 18, lx2 = cell - ly * 18;
    const int gy = ty * 16 - 1 + ly, gx = tx * 16 - 1 + lx2;
    uint4 d = make_uint4(0u, 0u, 0u, 0u);
    if (((unsigned)gy < 64u) && ((unsigned)gx < 64u))
      d = *(const uint4*)(pb + (((size_t)gy << 6) + gx) * 32 + part * 8);
    *(uint4*)(As + (ly * 18 + lx2) * 40 + part * 8) = d;
  }
  for (int v = tid; v < 1152; v += 256) {
    const int r = v >> 2, part = v & 3;
    const int t = r >> 5, n = r & 31;
    const uint4 d = *(const uint4*)(k2pb + (size_t)b * 18432 +
                                    ((size_t)(t * 64 + cog * 32 + n)) * 32 + part * 8);
    *(uint4*)(Bs + r * 40 + part * 8) = d;
  }
  __syncthreads();

  const int w = tid >> 6;
  const int lane = tid & 63;
  const int lx = lane & 15, lg = lane >> 4;

  f4 acc[4][2];
#pragma unroll
  for (int mt = 0; mt < 4; ++mt)
#pragma unroll
    for (int nt = 0; nt < 2; ++nt)
      acc[mt][nt] = (f4){0.f, 0.f, 0.f, 0.f};

#pragma unroll
  for (int t = 0; t < 9; ++t) {
    const int ky = t / 3, kx = t - 3 * (t / 3);
    bf8 Bf0 = *(const bf8*)(Bs + ((t << 5) + lx) * 40 + (lg << 3));
    bf8 Bf1 = *(const bf8*)(Bs + ((t << 5) + 16 + lx) * 40 + (lg << 3));
#pragma unroll
    for (int mt = 0; mt < 4; ++mt) {
      const int y = 4 * w + mt + ky;
      const bf8 Af = *(const bf8*)(As + (y * 18 + lx + kx) * 40 + (lg << 3));
      acc[mt][0] = __builtin_amdgcn_mfma_f32_16x16x32_bf16(Af, Bf0, acc[mt][0], 0, 0, 0);
      acc[mt][1] = __builtin_amdgcn_mfma_f32_16x16x32_bf16(Af, Bf1, acc[mt][1], 0, 0, 0);
    }
  }

  // epilogue: pooled value per (half,q,nt); predicated S3 partial sums.
  float s3[2][9];
#pragma unroll
  for (int nt = 0; nt < 2; ++nt)
#pragma unroll
    for (int t = 0; t < 9; ++t) s3[nt][t] = 0.f;

#pragma unroll
  for (int half = 0; half < 2; ++half) {
    const int prow = ty * 8 + 2 * w + half;
    const bool rok0 = (prow < 31), rok2 = (prow > 0);
#pragma unroll
    for (int q = 0; q < 2; ++q) {
      const int pcol = tx * 8 + 2 * lg + q;
      const bool cok0 = (pcol < 31), cok2 = (pcol > 0);
      const bool rok[3] = {rok0, true, rok2};
      const bool cok[3] = {cok0, true, cok2};
#pragma unroll
      for (int nt = 0; nt < 2; ++nt) {
        const int co = cog * 32 + nt * 16 + lx;
        const float inv = gamma[co] * rsqrtf(bnvar[co] + EPSBN);
        const float bias = beta[co] - bnmean[co] * inv;
        const float m0 = fmaxf(acc[2 * half][nt][2 * q] + bias, 0.f);
        const float m1 = fmaxf(acc[2 * half][nt][2 * q + 1] + bias, 0.f);
        const float m2 = fmaxf(acc[2 * half + 1][nt][2 * q] + bias, 0.f);
        const float m3 = fmaxf(acc[2 * half + 1][nt][2 * q + 1] + bias, 0.f);
        const float mx = fmaxf(fmaxf(m0, m1), fmaxf(m2, m3));
#pragma unroll
        for (int ky = 0; ky < 3; ++ky)
#pragma unroll
          for (int kx = 0; kx < 3; ++kx)
            if (rok[ky] && cok[kx]) s3[nt][ky * 3 + kx] += mx;
      }
    }
  }

  // reduce s3 over lg (lanes ^16 ^32); lane lg==0 holds per-wave partials
#pragma unroll
  for (int nt = 0; nt < 2; ++nt)
#pragma unroll
    for (int t = 0; t < 9; ++t) {
      float v = s3[nt][t];
      v += __shfl_xor(v, 16, 64);
      v += __shfl_xor(v, 32, 64);
      s3[nt][t] = v;
    }
  __syncthreads();  // all waves done with As/Bs + sred safe
  if (lg == 0) {
#pragma unroll
    for (int nt = 0; nt < 2; ++nt)
#pragma unroll
      for (int t = 0; t < 9; ++t) sred[w][nt][lx][t] = s3[nt][t];
  }
  __syncthreads();
  for (int v = tid; v < 288; v += 256) {
    const int tap = v >> 5;        // 0..8
    const int colocal = v & 31;    // nt*16+lx
    const int nt = colocal >> 4, lxx = colocal & 15;
    part_s3[(size_t)bi * 288 + v] =
        sred[0][nt][lxx][tap] + sred[1][nt][lxx][tap] +
        sred[2][nt][lxx][tap] + sred[3][nt][lxx][tap];
  }
}

// ------------- K: S3 finish + SE2 + route3 + contraction + BN3 (per-batch) -----
// grid 64, block 512 (8 waves). 4-way tap split for the expert contraction.
__global__ __launch_bounds__(512)
void k_final(const float* __restrict__ part_s3, const float* __restrict__ experts3,
             const float* __restrict__ rw, const float* __restrict__ rb,
             const float* __restrict__ w1, const float* __restrict__ w2,
             const float* __restrict__ gamma, const float* __restrict__ beta,
             const float* __restrict__ bnmean, const float* __restrict__ bnvar,
             float* __restrict__ out) {
  const int b = blockIdx.x;
  const int tid = threadIdx.x;
  __shared__ float S_loc[9][64], Sp[9][64], m2[64], h[4], s2[64], route[3], redf[4][128];

  for (int v = tid; v < 576; v += 512) {
    const int tap = v >> 6, ci = v & 63;
    const int cg = ci >> 5, colocal = ci & 31;
    float s = 0.f;
#pragma unroll
    for (int tile = 0; tile < 16; ++tile)
      s += part_s3[(size_t)((b * 16 + tile) * 2 + cg) * 288 + tap * 32 + colocal];
    S_loc[tap][ci] = s;
  }
  __syncthreads();
  if (tid < 64) m2[tid] = S_loc[4][tid] * (1.0f / 1024.0f);
  __syncthreads();
  if (tid < 4) {
    float z = 0.f;
    for (int c = 0; c < 64; ++c) z += m2[c] * w1[c * 4 + tid];
    h[tid] = fmaxf(z, 0.f);
  }
  __syncthreads();
  if (tid < 64) {
    float z = 0.f;
#pragma unroll
    for (int j = 0; j < 4; ++j) z += h[j] * w2[j * 64 + tid];
    s2[tid] = sigmoidf_(z);
  }
  __syncthreads();
  if (tid < 3) {
    float z = rb[tid];
    for (int c = 0; c < 64; ++c) z += m2[c] * s2[c] * rw[c * 3 + tid];
    route[tid] = sigmoidf_(z);
  }
  __syncthreads();
  for (int v = tid; v < 576; v += 512) {
    const int tap = v >> 6, ci = v & 63;
    Sp[tap][ci] = S_loc[tap][ci] * s2[ci];
  }
  __syncthreads();

  const int co = tid & 127;
  const int quarter = tid >> 7;                    // 0..3
  const int tap_lo = (quarter == 0) ? 0 : (2 * quarter + 1);
  const int tap_hi = tap_lo + ((quarter == 0) ? 3 : 2);
  float acc = 0.f;
#pragma unroll
  for (int e = 0; e < 3; ++e) {
    float m = 0.f;
    for (int tap = tap_lo; tap < tap_hi; ++tap) {
      const float* E = experts3 + ((size_t)(e * 9 + tap) * 64) * 128 + co;
#pragma unroll 16
      for (int ci = 0; ci < 64; ++ci) m = fmaf(E[(size_t)ci * 128], Sp[tap][ci], m);
    }
    acc += route[e] * m;
  }
  redf[quarter][co] = acc;
  __syncthreads();
  if (tid < 128) {
    const float total = redf[0][tid] + redf[1][tid] + redf[2][tid] + redf[3][tid];
    const float inv = gamma[tid] * rsqrtf(bnvar[tid] + EPSBN);
    out[(size_t)b * 128 + tid] = total * (1.0f / 1024.0f) * inv + (beta[tid] - bnmean[tid] * inv);
  }
}

extern "C" void kernel_launch(void* const* d_in, const int* in_sizes, int n_in,
                              void* d_out, int out_size, void* d_ws, size_t ws_size,
                              hipStream_t stream) {
  const float* x        = (const float*)d_in[0];
  const float* experts1 = (const float*)d_in[1];
  const float* rw1      = (const float*)d_in[2];
  const float* rb1      = (const float*)d_in[3];
  const float* g1  = (const float*)d_in[4];
  const float* be1 = (const float*)d_in[5];
  const float* mu1 = (const float*)d_in[6];
  const float* va1 = (const float*)d_in[7];
  const float* sw1a = (const float*)d_in[8];
  const float* sw1b = (const float*)d_in[9];
  const float* experts2 = (const float*)d_in[10];
  const float* rw2 = (const float*)d_in[11];
  const float* rb2 = (const float*)d_in[12];
  const float* g2  = (const float*)d_in[13];
  const float* be2 = (const float*)d_in[14];
  const float* mu2 = (const float*)d_in[15];
  const float* va2 = (const float*)d_in[16];
  const float* sw2a = (const float*)d_in[17];
  const float* sw2b = (const float*)d_in[18];
  const float* experts3 = (const float*)d_in[19];
  const float* rw3 = (const float*)d_in[20];
  const float* rb3 = (const float*)d_in[21];
  const float* g3  = (const float*)d_in[22];
  const float* be3 = (const float*)d_in[23];
  const float* mu3 = (const float*)d_in[24];
  const float* va3 = (const float*)d_in[25];
  float* out = (float*)d_out;
  float* ws = (float*)d_ws;

  // workspace layout (float offsets, all 16B-aligned):
  float* meanx_part = ws;                          // 1536
  float* part_m1    = ws + 1536;                   // 16384  [512][32]
  ushort_t* k1b     = (ushort_t*)(ws + 17920);     // 196,608 shorts = 98,304 fl
  ushort_t* k2pb    = (ushort_t*)(ws + 116224);    // 1,179,648 shorts = 589,824 fl
  float* part_s3    = ws + 706048;                 // 589,824  [2048][288]
  ushort_t* p1b     = (ushort_t*)(ws + 1295872);   // 8,388,608 shorts = 4,194,304 fl
  // end: 5,490,176 floats = 22.0 MB

  hipLaunchKernelGGL(k_mean_x, dim3(256), dim3(256), 0, stream, x, meanx_part);
  hipLaunchKernelGGL(k_buildk1, dim3(64), dim3(256), 0, stream,
                     meanx_part, experts1, rw1, rb1, g1, va1, k1b);
  hipLaunchKernelGGL(k_conv1, dim3(512), dim3(256), 0, stream,
                     x, k1b, g1, be1, mu1, va1, p1b, part_m1);
  hipLaunchKernelGGL(k_buildk2, dim3(64), dim3(256), 0, stream,
                     part_m1, experts2, rw2, rb2, sw1a, sw1b, g2, va2, k2pb);
  hipLaunchKernelGGL(k_conv2, dim3(2048), dim3(256), 0, stream,
                     p1b, k2pb, g2, be2, mu2, va2, part_s3);
  hipLaunchKernelGGL(k_final, dim3(64), dim3(512), 0, stream,
                     part_s3, experts3, rw3, rb3, sw2a, sw2b, g3, be3, mu3, va3, out);
}

// Round 5
// 187.904 us; speedup vs baseline: 1.7792x; 1.1034x over previous
//
#include <hip/hip_runtime.h>

#define EPSBN 1e-3f

typedef unsigned short ushort_t;
typedef __attribute__((ext_vector_type(8))) short bf8;   // 8 bf16 = 4 VGPRs
typedef __attribute__((ext_vector_type(4))) float f4;

__device__ __forceinline__ float sigmoidf_(float z) {
  return 1.0f / (1.0f + expf(-z));
}

__device__ __forceinline__ ushort_t f2bf(float x) {  // RTNE
  union { float f; unsigned u; } v; v.f = x;
  unsigned r = (v.u + 0x7fffu + ((v.u >> 16) & 1u)) >> 16;
  return (ushort_t)r;
}

// ---------------- K: partial channel sums of x (256 blocks = b*4+q) ------------
// Each thread handles 24 consecutive floats (channel = idx%6 is compile-time).
__global__ void k_mean_x(const float* __restrict__ x, float* __restrict__ part) {
  const int b = blockIdx.x >> 2;
  const int q = blockIdx.x & 3;
  const int tid = threadIdx.x;
  float acc[6] = {0.f, 0.f, 0.f, 0.f, 0.f, 0.f};
  const float* xb = x + (size_t)b * 98304 + (size_t)q * 24576;
  for (int p = 0; p < 4; ++p) {
    const float* base = xb + (size_t)p * 6144 + (size_t)tid * 24;
#pragma unroll
    for (int k = 0; k < 6; ++k) {
      const float4 v = *(const float4*)(base + k * 4);
      acc[(4 * k + 0) % 6] += v.x;
      acc[(4 * k + 1) % 6] += v.y;
      acc[(4 * k + 2) % 6] += v.z;
      acc[(4 * k + 3) % 6] += v.w;
    }
  }
#pragma unroll
  for (int c = 0; c < 6; ++c)
    for (int off = 32; off > 0; off >>= 1) acc[c] += __shfl_down(acc[c], off, 64);
  __shared__ float red[4][6];
  const int lane = tid & 63, w = tid >> 6;
  if (lane == 0) {
#pragma unroll
    for (int c = 0; c < 6; ++c) red[w][c] = acc[c];
  }
  __syncthreads();
  if (tid < 6) {
    part[blockIdx.x * 6 + tid] = red[0][tid] + red[1][tid] + red[2][tid] + red[3][tid];
  }
}

// ------------- K: conv1 (fused route1/buildk1) MFMA + BN + relu + pool + mean1 -
// grid: 64 b x 4 row-tiles x 2 col-tiles = 512 blocks.
__global__ __launch_bounds__(256)
void k_conv1(const float* __restrict__ x, const float* __restrict__ meanx_part,
             const float* __restrict__ experts1,
             const float* __restrict__ rw, const float* __restrict__ rbias,
             const float* __restrict__ gamma, const float* __restrict__ beta,
             const float* __restrict__ bnmean, const float* __restrict__ bnvar,
             ushort_t* __restrict__ p1b, float* __restrict__ part_m1) {
  const int bid = blockIdx.x;
  const int b = bid >> 3;
  const int tyi = (bid >> 1) & 3;
  const int txi = bid & 1;
  __shared__ __align__(16) ushort_t patch[34 * 68 * 8];  // 36,992 B
  __shared__ float route_s[3];
  __shared__ float mred[4][32];
  const int tid = threadIdx.x;
  const float* xb = x + (size_t)b * (128 * 128 * 6);

  if (tid < 3) {
    float z = rbias[tid];
    for (int c = 0; c < 6; ++c) {
      const float s = meanx_part[(b * 4 + 0) * 6 + c] + meanx_part[(b * 4 + 1) * 6 + c] +
                      meanx_part[(b * 4 + 2) * 6 + c] + meanx_part[(b * 4 + 3) * 6 + c];
      z += (s * (1.0f / 16384.0f)) * rw[c * 3 + tid];
    }
    route_s[tid] = sigmoidf_(z);
  }

  for (int v = tid; v < 34 * 68; v += 256) {
    const int ry = v / 68, p = v - ry * 68;
    const int gy = tyi * 32 - 1 + ry, gx = txi * 64 - 1 + p;
    uint4 u = make_uint4(0u, 0u, 0u, 0u);
    if (((unsigned)gy < 128u) && ((unsigned)gx < 128u)) {
      const float* s = xb + ((size_t)(gy * 128 + gx)) * 6;
      const float2 a0 = *(const float2*)s;
      const float2 a1 = *(const float2*)(s + 2);
      const float2 a2 = *(const float2*)(s + 4);
      u.x = (unsigned)f2bf(a0.x) | ((unsigned)f2bf(a0.y) << 16);
      u.y = (unsigned)f2bf(a1.x) | ((unsigned)f2bf(a1.y) << 16);
      u.z = (unsigned)f2bf(a2.x) | ((unsigned)f2bf(a2.y) << 16);
      u.w = 0u;
    }
    *(uint4*)(patch + (size_t)v * 8) = u;
  }
  __syncthreads();

  const int w = tid >> 6;
  const int lane = tid & 63;
  const int lx = lane & 15, lg = lane >> 4;

  const float r0 = route_s[0], r1 = route_s[1], r2 = route_s[2];
  const int co0 = lx, co1 = 16 + lx;
  const float inv0 = gamma[co0] * rsqrtf(bnvar[co0] + EPSBN);
  const float bias0 = beta[co0] - bnmean[co0] * inv0;
  const float inv1 = gamma[co1] * rsqrtf(bnvar[co1] + EPSBN);
  const float bias1 = beta[co1] - bnmean[co1] * inv1;

  // build B fragments in-register: Bf[ky][nt][j] = W'[kx=lg][ci=j][co=nt*16+lx]
  bf8 Bf[3][2];
#pragma unroll
  for (int ky = 0; ky < 3; ++ky) {
#pragma unroll
    for (int nt = 0; nt < 2; ++nt) {
      const int co = nt * 16 + lx;
      const float inv = nt ? inv1 : inv0;
#pragma unroll
      for (int j = 0; j < 8; ++j) {
        float val = 0.f;
        if (j < 6 && lg < 3) {
          const int idx = ((ky * 3 + lg) * 6 + j) * 32 + co;
          val = (r0 * experts1[idx] + r1 * experts1[1728 + idx] +
                 r2 * experts1[3456 + idx]) * inv;
        }
        Bf[ky][nt][j] = (short)f2bf(val);
      }
    }
  }

  float msum0 = 0.f, msum1 = 0.f;

#pragma unroll
  for (int xt = 0; xt < 4; ++xt) {
    bf8 Af[10];
#pragma unroll
    for (int r = 0; r < 10; ++r)
      Af[r] = *(const bf8*)(patch + ((size_t)(w * 8 + r) * 68 + xt * 16 + lx + lg) * 8);
#pragma unroll
    for (int rp = 0; rp < 4; ++rp) {
      const int prow = tyi * 16 + w * 4 + rp;
      f4 acc0[2], acc1[2];
#pragma unroll
      for (int nt = 0; nt < 2; ++nt) {
        acc0[nt] = (f4){0.f, 0.f, 0.f, 0.f};
        acc1[nt] = (f4){0.f, 0.f, 0.f, 0.f};
      }
#pragma unroll
      for (int ky = 0; ky < 3; ++ky) {
#pragma unroll
        for (int nt = 0; nt < 2; ++nt) {
          acc0[nt] = __builtin_amdgcn_mfma_f32_16x16x32_bf16(Af[rp * 2 + ky], Bf[ky][nt], acc0[nt], 0, 0, 0);
          acc1[nt] = __builtin_amdgcn_mfma_f32_16x16x32_bf16(Af[rp * 2 + ky + 1], Bf[ky][nt], acc1[nt], 0, 0, 0);
        }
      }
#pragma unroll
      for (int nt = 0; nt < 2; ++nt) {
        const float bias = nt ? bias1 : bias0;
        const int co = nt * 16 + lx;
#pragma unroll
        for (int q = 0; q < 2; ++q) {
          const float m0 = fmaxf(acc0[nt][2 * q] + bias, 0.f);
          const float m1 = fmaxf(acc0[nt][2 * q + 1] + bias, 0.f);
          const float m2 = fmaxf(acc1[nt][2 * q] + bias, 0.f);
          const float m3 = fmaxf(acc1[nt][2 * q + 1] + bias, 0.f);
          const float mx = fmaxf(fmaxf(m0, m1), fmaxf(m2, m3));
          if (nt) msum1 += mx; else msum0 += mx;
          const int pcol = txi * 32 + xt * 8 + lg * 2 + q;
          p1b[(((size_t)b * 64 + prow) * 64 + pcol) * 32 + co] = f2bf(mx);
        }
      }
    }
  }

  msum0 += __shfl_xor(msum0, 16, 64);
  msum0 += __shfl_xor(msum0, 32, 64);
  msum1 += __shfl_xor(msum1, 16, 64);
  msum1 += __shfl_xor(msum1, 32, 64);
  if (lg == 0) {
    mred[w][lx] = msum0;
    mred[w][16 + lx] = msum1;
  }
  __syncthreads();
  if (tid < 32) {
    part_m1[(size_t)bid * 32 + tid] =
        mred[0][tid] + mred[1][tid] + mred[2][tid] + mred[3][tid];
  }
}

// ------------- K: SE1 + route2 + build k2' bf16 [b][tap][co][ci] (192 blocks) --
__global__ void k_buildk2(const float* __restrict__ part_m1,
                          const float* __restrict__ experts2,
                          const float* __restrict__ rw, const float* __restrict__ rb,
                          const float* __restrict__ w1, const float* __restrict__ w2,
                          const float* __restrict__ gamma, const float* __restrict__ var,
                          ushort_t* __restrict__ k2pb) {
  const int b = blockIdx.x / 3;
  const int seg = blockIdx.x - b * 3;
  const int tid = threadIdx.x;
  __shared__ float m1[32], h[2], s1[32], route[3];
  if (tid < 32) {
    float s = 0.f;
#pragma unroll
    for (int k = 0; k < 8; ++k) s += part_m1[(size_t)(b * 8 + k) * 32 + tid];
    m1[tid] = s * (1.0f / 4096.0f);
  }
  __syncthreads();
  if (tid < 2) {
    float z = 0.f;
    for (int c = 0; c < 32; ++c) z += m1[c] * w1[c * 2 + tid];
    h[tid] = fmaxf(z, 0.f);
  }
  __syncthreads();
  if (tid < 32) s1[tid] = sigmoidf_(h[0] * w2[tid] + h[1] * w2[32 + tid]);
  __syncthreads();
  if (tid < 3) {
    float z = rb[tid];
    for (int c = 0; c < 32; ++c) z += m1[c] * s1[c] * rw[c * 3 + tid];
    route[tid] = sigmoidf_(z);
  }
  __syncthreads();
  const float r0 = route[0], r1 = route[1], r2 = route[2];
  const int t_lo = seg * 6144, t_hi = t_lo + 6144;
  for (int t = t_lo + tid; t < t_hi; t += 256) {
    const int co = t & 63;
    const int ci = (t >> 6) & 31;
    const int tap = t >> 11;
    const float inv = gamma[co] * rsqrtf(var[co] + EPSBN);
    const float v = r0 * experts2[t] + r1 * experts2[18432 + t] + r2 * experts2[2 * 18432 + t];
    k2pb[(size_t)b * 18432 + ((size_t)tap * 64 + co) * 32 + ci] = f2bf(v * s1[ci] * inv);
  }
}

// ------------- K: conv2 MFMA + BN + relu + pool + S3 boundary aggregates -------
// grid: 64 b x 16 tiles x 2 cog. Emits 9 aggregates (t,r0,rl,c0,cl,k00,k01,k10,k11)
// per (tile,cog,co_local) into part_s3[bi*288 + agg*32 + co_local].
__global__ __launch_bounds__(256)
void k_conv2(const ushort_t* __restrict__ p1b, const ushort_t* __restrict__ k2pb,
             const float* __restrict__ gamma, const float* __restrict__ beta,
             const float* __restrict__ bnmean, const float* __restrict__ bnvar,
             float* __restrict__ part_s3) {
  const int bi = blockIdx.x;
  const int b = bi >> 5;
  const int tile = (bi >> 1) & 15;
  const int cog = bi & 1;
  const int ty = tile >> 2, tx = tile & 3;
  __shared__ __align__(16) short smem[24480];  // As 12960 + Bs 11520 shorts
  short* As = smem;
  short* Bs = smem + 12960;
  const int tid = threadIdx.x;

  const ushort_t* pb = p1b + (size_t)b * 131072;
  for (int v = tid; v < 1296; v += 256) {
    const int cell = v >> 2, part = v & 3;
    const int ly = cell / 18, lx2 = cell - ly * 18;
    const int gy = ty * 16 - 1 + ly, gx = tx * 16 - 1 + lx2;
    uint4 d = make_uint4(0u, 0u, 0u, 0u);
    if (((unsigned)gy < 64u) && ((unsigned)gx < 64u))
      d = *(const uint4*)(pb + (((size_t)gy << 6) + gx) * 32 + part * 8);
    *(uint4*)(As + (ly * 18 + lx2) * 40 + part * 8) = d;
  }
  for (int v = tid; v < 1152; v += 256) {
    const int r = v >> 2, part = v & 3;
    const int t = r >> 5, n = r & 31;
    const uint4 d = *(const uint4*)(k2pb + (size_t)b * 18432 +
                                    ((size_t)(t * 64 + cog * 32 + n)) * 32 + part * 8);
    *(uint4*)(Bs + r * 40 + part * 8) = d;
  }
  __syncthreads();

  const int w = tid >> 6;
  const int lane = tid & 63;
  const int lx = lane & 15, lg = lane >> 4;

  f4 acc[4][2];
#pragma unroll
  for (int mt = 0; mt < 4; ++mt)
#pragma unroll
    for (int nt = 0; nt < 2; ++nt)
      acc[mt][nt] = (f4){0.f, 0.f, 0.f, 0.f};

  // kx-outer: 6 A-rows serve 3 ky x 4 mt
#pragma unroll
  for (int kx = 0; kx < 3; ++kx) {
    bf8 Af[6];
#pragma unroll
    for (int r = 0; r < 6; ++r)
      Af[r] = *(const bf8*)(As + ((4 * w + r) * 18 + lx + kx) * 40 + (lg << 3));
#pragma unroll
    for (int ky = 0; ky < 3; ++ky) {
      const int t = ky * 3 + kx;
      const bf8 Bf0 = *(const bf8*)(Bs + ((t << 5) + lx) * 40 + (lg << 3));
      const bf8 Bf1 = *(const bf8*)(Bs + ((t << 5) + 16 + lx) * 40 + (lg << 3));
#pragma unroll
      for (int mt = 0; mt < 4; ++mt) {
        acc[mt][0] = __builtin_amdgcn_mfma_f32_16x16x32_bf16(Af[ky + mt], Bf0, acc[mt][0], 0, 0, 0);
        acc[mt][1] = __builtin_amdgcn_mfma_f32_16x16x32_bf16(Af[ky + mt], Bf1, acc[mt][1], 0, 0, 0);
      }
    }
  }

  // epilogue: BN consts hoisted; 9 boundary aggregates per nt.
  float inv[2], bias[2];
#pragma unroll
  for (int nt = 0; nt < 2; ++nt) {
    const int co = cog * 32 + nt * 16 + lx;
    inv[nt] = gamma[co] * rsqrtf(bnvar[co] + EPSBN);
    bias[nt] = beta[co] - bnmean[co] * inv[nt];
  }
  float agg[2][9];
#pragma unroll
  for (int nt = 0; nt < 2; ++nt)
#pragma unroll
    for (int a = 0; a < 9; ++a) agg[nt][a] = 0.f;

#pragma unroll
  for (int half = 0; half < 2; ++half) {
    const int prow = ty * 8 + 2 * w + half;
    const bool rT = (prow == 0), rB = (prow == 31);
#pragma unroll
    for (int q = 0; q < 2; ++q) {
      const int pcol = tx * 8 + 2 * lg + q;
      const bool cL = (pcol == 0), cR = (pcol == 31);
#pragma unroll
      for (int nt = 0; nt < 2; ++nt) {
        const float m0 = fmaxf(acc[2 * half][nt][2 * q] + bias[nt], 0.f);
        const float m1 = fmaxf(acc[2 * half][nt][2 * q + 1] + bias[nt], 0.f);
        const float m2 = fmaxf(acc[2 * half + 1][nt][2 * q] + bias[nt], 0.f);
        const float m3 = fmaxf(acc[2 * half + 1][nt][2 * q + 1] + bias[nt], 0.f);
        const float mx = fmaxf(fmaxf(m0, m1), fmaxf(m2, m3));
        agg[nt][0] += mx;
        if (rT) agg[nt][1] += mx;
        if (rB) agg[nt][2] += mx;
        if (cL) agg[nt][3] += mx;
        if (cR) agg[nt][4] += mx;
        if (rT && cL) agg[nt][5] += mx;  // k00
        if (rT && cR) agg[nt][6] += mx;  // k01
        if (rB && cL) agg[nt][7] += mx;  // k10
        if (rB && cR) agg[nt][8] += mx;  // k11
      }
    }
  }

#pragma unroll
  for (int nt = 0; nt < 2; ++nt)
#pragma unroll
    for (int a = 0; a < 9; ++a) {
      float v = agg[nt][a];
      v += __shfl_xor(v, 16, 64);
      v += __shfl_xor(v, 32, 64);
      agg[nt][a] = v;
    }
  __syncthreads();  // done with As/Bs; reuse smem for reduction
  float* sred = (float*)smem;  // [w][nt][lx][agg] = [4][2][16][9]
  if (lg == 0) {
#pragma unroll
    for (int nt = 0; nt < 2; ++nt)
#pragma unroll
      for (int a = 0; a < 9; ++a)
        sred[((w * 2 + nt) * 16 + lx) * 9 + a] = agg[nt][a];
  }
  __syncthreads();
  for (int v = tid; v < 288; v += 256) {
    const int a = v >> 5;          // aggregate 0..8
    const int colocal = v & 31;    // nt*16+lx
    const int nt = colocal >> 4, lxx = colocal & 15;
    float s = 0.f;
#pragma unroll
    for (int ww = 0; ww < 4; ++ww) s += sred[((ww * 2 + nt) * 16 + lxx) * 9 + a];
    part_s3[(size_t)bi * 288 + v] = s;
  }
}

// ------------- K: S3 reconstruct + SE2 + route3 + contraction + BN3 ------------
__global__ __launch_bounds__(512)
void k_final(const float* __restrict__ part_s3, const float* __restrict__ experts3,
             const float* __restrict__ rw, const float* __restrict__ rb,
             const float* __restrict__ w1, const float* __restrict__ w2,
             const float* __restrict__ gamma, const float* __restrict__ beta,
             const float* __restrict__ bnmean, const float* __restrict__ bnvar,
             float* __restrict__ out) {
  const int b = blockIdx.x;
  const int tid = threadIdx.x;
  __shared__ float AG[9][64], Sp[9][64], m2[64], h[4], s2[64], route[3], redf[4][128];

  for (int v = tid; v < 576; v += 512) {
    const int a = v >> 6, ci = v & 63;
    const int cg = ci >> 5, colocal = ci & 31;
    float s = 0.f;
#pragma unroll
    for (int tile = 0; tile < 16; ++tile)
      s += part_s3[(size_t)((b * 16 + tile) * 2 + cg) * 288 + a * 32 + colocal];
    AG[a][ci] = s;
  }
  __syncthreads();
  if (tid < 64) m2[tid] = AG[0][tid] * (1.0f / 1024.0f);
  __syncthreads();
  if (tid < 4) {
    float z = 0.f;
    for (int c = 0; c < 64; ++c) z += m2[c] * w1[c * 4 + tid];
    h[tid] = fmaxf(z, 0.f);
  }
  __syncthreads();
  if (tid < 64) {
    float z = 0.f;
#pragma unroll
    for (int j = 0; j < 4; ++j) z += h[j] * w2[j * 64 + tid];
    s2[tid] = sigmoidf_(z);
  }
  __syncthreads();
  if (tid < 3) {
    float z = rb[tid];
    for (int c = 0; c < 64; ++c) z += m2[c] * s2[c] * rw[c * 3 + tid];
    route[tid] = sigmoidf_(z);
  }
  __syncthreads();
  // reconstruct shifted sums: S = T - A[ky] - B[kx] + AB[ky][kx]
  for (int v = tid; v < 576; v += 512) {
    const int tap = v >> 6, ci = v & 63;
    const int ky = tap / 3, kx = tap - 3 * ky;
    const float T = AG[0][ci];
    const float A = (ky == 0) ? AG[2][ci] : ((ky == 2) ? AG[1][ci] : 0.f);
    const float B = (kx == 0) ? AG[4][ci] : ((kx == 2) ? AG[3][ci] : 0.f);
    float AB = 0.f;
    if (ky == 0 && kx == 0) AB = AG[8][ci];        // k11
    else if (ky == 0 && kx == 2) AB = AG[7][ci];   // k10
    else if (ky == 2 && kx == 0) AB = AG[6][ci];   // k01
    else if (ky == 2 && kx == 2) AB = AG[5][ci];   // k00
    Sp[tap][ci] = (T - A - B + AB) * s2[ci];
  }
  __syncthreads();

  const int co = tid & 127;
  const int quarter = tid >> 7;
  const int tap_lo = (quarter == 0) ? 0 : (2 * quarter + 1);
  const int tap_hi = tap_lo + ((quarter == 0) ? 3 : 2);
  float acc = 0.f;
#pragma unroll
  for (int e = 0; e < 3; ++e) {
    float m = 0.f;
    for (int tap = tap_lo; tap < tap_hi; ++tap) {
      const float* E = experts3 + ((size_t)(e * 9 + tap) * 64) * 128 + co;
#pragma unroll 16
      for (int ci = 0; ci < 64; ++ci) m = fmaf(E[(size_t)ci * 128], Sp[tap][ci], m);
    }
    acc += route[e] * m;
  }
  redf[quarter][co] = acc;
  __syncthreads();
  if (tid < 128) {
    const float total = redf[0][tid] + redf[1][tid] + redf[2][tid] + redf[3][tid];
    const float inv = gamma[tid] * rsqrtf(bnvar[tid] + EPSBN);
    out[(size_t)b * 128 + tid] = total * (1.0f / 1024.0f) * inv + (beta[tid] - bnmean[tid] * inv);
  }
}

extern "C" void kernel_launch(void* const* d_in, const int* in_sizes, int n_in,
                              void* d_out, int out_size, void* d_ws, size_t ws_size,
                              hipStream_t stream) {
  const float* x        = (const float*)d_in[0];
  const float* experts1 = (const float*)d_in[1];
  const float* rw1      = (const float*)d_in[2];
  const float* rb1      = (const float*)d_in[3];
  const float* g1  = (const float*)d_in[4];
  const float* be1 = (const float*)d_in[5];
  const float* mu1 = (const float*)d_in[6];
  const float* va1 = (const float*)d_in[7];
  const float* sw1a = (const float*)d_in[8];
  const float* sw1b = (const float*)d_in[9];
  const float* experts2 = (const float*)d_in[10];
  const float* rw2 = (const float*)d_in[11];
  const float* rb2 = (const float*)d_in[12];
  const float* g2  = (const float*)d_in[13];
  const float* be2 = (const float*)d_in[14];
  const float* mu2 = (const float*)d_in[15];
  const float* va2 = (const float*)d_in[16];
  const float* sw2a = (const float*)d_in[17];
  const float* sw2b = (const float*)d_in[18];
  const float* experts3 = (const float*)d_in[19];
  const float* rw3 = (const float*)d_in[20];
  const float* rb3 = (const float*)d_in[21];
  const float* g3  = (const float*)d_in[22];
  const float* be3 = (const float*)d_in[23];
  const float* mu3 = (const float*)d_in[24];
  const float* va3 = (const float*)d_in[25];
  float* out = (float*)d_out;
  float* ws = (float*)d_ws;

  // workspace layout (float offsets, all 16B-aligned):
  float* meanx_part = ws;                           // 1536
  float* part_m1    = ws + 1536;                    // 16384  [512][32]
  ushort_t* k2pb    = (ushort_t*)(ws + 17920);      // 1,179,648 shorts = 589,824 fl
  float* part_s3    = ws + 607744;                  // 589,824  [2048][288]
  ushort_t* p1b     = (ushort_t*)(ws + 1197568);    // 8,388,608 shorts = 4,194,304 fl
  // end: 5,391,872 floats = 21.6 MB

  hipLaunchKernelGGL(k_mean_x, dim3(256), dim3(256), 0, stream, x, meanx_part);
  hipLaunchKernelGGL(k_conv1, dim3(512), dim3(256), 0, stream,
                     x, meanx_part, experts1, rw1, rb1, g1, be1, mu1, va1, p1b, part_m1);
  hipLaunchKernelGGL(k_buildk2, dim3(192), dim3(256), 0, stream,
                     part_m1, experts2, rw2, rb2, sw1a, sw1b, g2, va2, k2pb);
  hipLaunchKernelGGL(k_conv2, dim3(2048), dim3(256), 0, stream,
                     p1b, k2pb, g2, be2, mu2, va2, part_s3);
  hipLaunchKernelGGL(k_final, dim3(64), dim3(512), 0, stream,
                     part_s3, experts3, rw3, rb3, sw2a, sw2b, g3, be3, mu3, va3, out);
}